// Round 4
// baseline (1315.108 us; speedup 1.0000x reference)
//
#include <hip/hip_runtime.h>
#include <cstddef>
#include <cstdint>

// ---------------- constants ----------------
#define NB    2
#define NP    1024    // patches per image
#define DFEAT 256
#define DSTATE 16
#define NEDGE 1984    // grid edges: 31*63 + 31

typedef unsigned short ushortb;

// MFMA fragment types (gfx950 32x32x16 bf16)
typedef float fx16 __attribute__((ext_vector_type(16)));
typedef short s16x8 __attribute__((ext_vector_type(8)));

// ---------------- helpers ----------------
__device__ __forceinline__ float bf2f(unsigned short u){
  union { unsigned int i; float f; } c; c.i = ((unsigned int)u) << 16; return c.f;
}
__device__ __forceinline__ unsigned short f2bf(float f){
  union { float f; unsigned int i; } c; c.f = f;
  unsigned int u = c.i;
  unsigned int r = (u + 0x7fffu + ((u >> 16) & 1u)) >> 16;
  return (unsigned short)r;
}
// dtype-generic input load: isbf ? bf16[i] : fp32[i]
__device__ __forceinline__ float ldin(const void* p, size_t i, int isbf){
  return isbf ? bf2f(((const ushortb*)p)[i]) : ((const float*)p)[i];
}
__device__ __forceinline__ float gelu_f(float x){
  return 0.5f * x * (1.0f + erff(x * 0.70710678118654752f));
}
__device__ __forceinline__ unsigned int f2sort(float f){
  union { float f; unsigned int i; } c; c.f = f;
  return (c.i & 0x80000000u) ? ~c.i : (c.i | 0x80000000u);
}

// ---------------- ws layout (float element offsets) ----------------
constexpr size_t AL(size_t x){ return (x + 63) & ~(size_t)63; }
constexpr size_t O_W1    = 0;                       // 1728  conv1 w fp32
constexpr size_t O_B1    = AL(O_W1 + 1728);         // 64
constexpr size_t O_W2    = AL(O_B1 + 64);           // 73728 floats = 147456 bf16, FRAGMENT-MAJOR
                                                    //   chunked for K-split: sg = c*18 + tap*2 + ksub
constexpr size_t O_B2    = AL(O_W2 + 73728);        // 128
constexpr size_t O_FCW   = AL(O_B2 + 128);          // 32768 [df][128]
constexpr size_t O_FCB   = AL(O_FCW + 32768);       // 256
constexpr size_t O_WDW   = AL(O_FCB + 256);         // 65536 TRANSPOSED [k][df]
constexpr size_t O_WDB   = AL(O_WDW + 65536);       // 256
constexpr size_t O_BWO   = AL(O_WDB + 256);         // 4096 TRANSPOSED [k][s]
constexpr size_t O_BBO   = AL(O_BWO + 4096);        // 16
constexpr size_t O_CWO   = AL(O_BBO + 16);          // 4096 TRANSPOSED [k][s]
constexpr size_t O_CBO   = AL(O_CWO + 4096);        // 16
constexpr size_t O_OW    = AL(O_CBO + 16);          // 65536 TRANSPOSED [k][df]
constexpr size_t O_OB    = AL(O_OW + 65536);        // 256
constexpr size_t O_AF    = AL(O_OB + 256);          // 4096  A = -exp(A_log), [f][s]
constexpr size_t O_DD    = AL(O_AF + 4096);         // 256
constexpr size_t O_LNG   = AL(O_DD + 256);          // 256
constexpr size_t O_LNB   = AL(O_LNG + 256);         // 256
constexpr size_t O_FEATS = AL(O_LNB + 256);         // 2*1024*256
constexpr size_t O_GPROJ = AL(O_FEATS + (size_t)NB*NP*DFEAT); // 512
constexpr size_t O_GPRIM = AL(O_GPROJ + NB*DFEAT);  // 512
constexpr size_t O_RSEM  = AL(O_GPRIM + NB*DFEAT);  // 2048
constexpr size_t O_BFS   = AL(O_RSEM + NB*NP);      // 2048 (int)
constexpr size_t O_PAR   = AL(O_BFS + NB*NP);       // 2048 (int)
constexpr size_t O_X     = AL(O_PAR + NB*NP);       // 2*1024*256
constexpr size_t O_DELTA = AL(O_X + (size_t)NB*NP*DFEAT);
constexpr size_t O_BP    = AL(O_DELTA + (size_t)NB*NP*DFEAT); // 2*1024*16
constexpr size_t O_CP    = AL(O_BP + NB*NP*DSTATE);
constexpr size_t O_YR    = AL(O_CP + NB*NP*DSTATE); // 2*1024*256
constexpr size_t O_FLAG  = AL(O_YR + (size_t)NB*NP*DFEAT);    // 1 int: is-bf16 flag
constexpr size_t O_LVL   = AL(O_FLAG + 64);         // NB*1040 ints: [nlvl, loff[0..nlvl]]

// ---------------- K-1: sniff input dtype (bf16 vs fp32) from images buffer -----------
__global__ __launch_bounds__(256) void k_sniff(const void* img, float* ws)
{
  __shared__ int cnt;
  int tid = threadIdx.x;
  if (tid == 0) cnt = 0;
  __syncthreads();
  const ushortb* u = (const ushortb*)img;
  int local = 0;
  for (int k = 0; k < 16; k++){
    unsigned short v = u[tid * 16 + k];
    if (v == 0 || v == 0x8000u){ local++; continue; }
    float f = fabsf(bf2f(v));
    if (f >= 1e-8f && f <= 64.f) local++;    // plausible N(0,1) bf16
  }
  atomicAdd(&cnt, local);
  __syncthreads();
  if (tid == 0) ((int*)(ws + O_FLAG))[0] = (cnt >= 3900) ? 1 : 0;  // >=95% plausible
}

// ---------------- K0: convert weights + zero YR + g_proj/g_prime (all fused) ---------
// blocks [0,990): weight convert; [990,3038): YR zero; [3038,3294): gmm rows.
__global__ __launch_bounds__(256) void k_convert(const void* c1w, const void* c1b, const void* c2w,
                          const void* c2b, const void* fcw, const void* fcb,
                          const void* alog, const void* dvec,
                          const void* bw, const void* bb, const void* cw, const void* cb,
                          const void* wdw, const void* wdb,
                          const void* ow, const void* ob,
                          const void* lng, const void* lnb,
                          const void* lang, const void* wgate, const void* wgp,
                          float* ws)
{
  const int F = ((const int*)(ws + O_FLAG))[0];
  if (blockIdx.x >= 3038){  // gmm branch: wave-per-row coalesced dual GEMV
    int row = (blockIdx.x - 3038) * 4 + (threadIdx.x >> 6);
    int lane = threadIdx.x & 63;
    int mat = row >> 9;
    int b   = (row >> 8) & 1;
    int df  = row & 255;
    const void* W = mat ? wgp : wgate;
    float s = 0.f;
    for (int k = lane; k < 896; k += 64)
      s += ldin(lang, (size_t)b * 896 + k, F) * ldin(W, (size_t)df * 896 + k, F);
    s += __shfl_xor(s, 1);  s += __shfl_xor(s, 2);  s += __shfl_xor(s, 4);
    s += __shfl_xor(s, 8);  s += __shfl_xor(s, 16); s += __shfl_xor(s, 32);
    if (lane == 0) ws[(mat ? O_GPRIM : O_GPROJ) + b * 256 + df] = s;
    return;
  }
  if (blockIdx.x >= 990){   // init branch: zero YR
    size_t i2 = (size_t)(blockIdx.x - 990) * 256 + threadIdx.x;
    if (i2 < (size_t)NB * NP * DFEAT) ws[O_YR + i2] = 0.f;
    return;
  }
  int i = blockIdx.x * 256 + threadIdx.x;
  if (i < 1728){ ws[O_W1 + i] = ldin(c1w, i, F); return; } i -= 1728;
  if (i < 64){ ws[O_B1 + i] = ldin(c1b, i, F); return; } i -= 64;
  if (i < 73728){
    // fragment-major bf16-split conv2 weights for chunked 32x32x16 MFMA.
    // step sg = c*18 + tap*2 + ksub (c = ic chunk of 32).
    // lane ln holds oc = nt*32 + (ln&31), k-in-step = (ln>>5)*8 + e.
    int sg = i >> 11;           // 0..35
    int r = i & 2047;
    int nt = r >> 9;
    int r2 = r & 511;           // ln*8 + e
    int ln = r2 >> 3, e = r2 & 7;
    int c  = sg / 18, s = sg - c * 18;
    int tap = s >> 1, ksub = s & 1;
    int oc = nt * 32 + (ln & 31);
    int ic = c * 32 + ksub * 16 + (ln >> 5) * 8 + e;
    float v = ldin(c2w, (size_t)(oc * 64 + ic) * 9 + tap, F);
    ushortb hi = f2bf(v);
    float lo = v - bf2f(hi);
    ushortb* WB = (ushortb*)(ws + O_W2);
    size_t cb = ((size_t)(sg * 4 + nt)) * 2;
    WB[cb * 512 + r2]       = hi;         // plane 0
    WB[(cb + 1) * 512 + r2] = f2bf(lo);   // plane 1
    return;
  } i -= 73728;
  if (i < 128){ ws[O_B2 + i] = ldin(c2b, i, F); return; } i -= 128;
  if (i < 32768){ ws[O_FCW + i] = ldin(fcw, i, F); return; } i -= 32768;
  if (i < 256){ ws[O_FCB + i] = ldin(fcb, i, F); return; } i -= 256;
  if (i < 65536){  // WDW transposed: dst[k*256+df] = src[df*256+k]
    int k = i >> 8, df = i & 255;
    ws[O_WDW + i] = ldin(wdw, (size_t)df * 256 + k, F); return;
  } i -= 65536;
  if (i < 256){ ws[O_WDB + i] = ldin(wdb, i, F); return; } i -= 256;
  if (i < 4096){   // B_w transposed: dst[k*16+s] = src[s*256+k]
    int k = i >> 4, s = i & 15;
    ws[O_BWO + i] = ldin(bw, (size_t)s * 256 + k, F); return;
  } i -= 4096;
  if (i < 16){ ws[O_BBO + i] = ldin(bb, i, F); return; } i -= 16;
  if (i < 4096){   // C_w transposed
    int k = i >> 4, s = i & 15;
    ws[O_CWO + i] = ldin(cw, (size_t)s * 256 + k, F); return;
  } i -= 4096;
  if (i < 16){ ws[O_CBO + i] = ldin(cb, i, F); return; } i -= 16;
  if (i < 65536){  // out_w transposed: dst[k*256+df] = src[df*256+k]
    int k = i >> 8, df = i & 255;
    ws[O_OW + i] = ldin(ow, (size_t)df * 256 + k, F); return;
  } i -= 65536;
  if (i < 256){ ws[O_OB + i] = ldin(ob, i, F); return; } i -= 256;
  if (i < 4096){ ws[O_AF + i] = -expf(ldin(alog, i, F)); return; } i -= 4096;
  if (i < 256){ ws[O_DD + i] = ldin(dvec, i, F); return; } i -= 256;
  if (i < 256){ ws[O_LNG + i] = ldin(lng, i, F); return; } i -= 256;
  if (i < 256){ ws[O_LNB + i] = ldin(lnb, i, F); }
}

// ---------------- K1: per-patch conv1 + MFMA conv2 (bf16 3-split, K-chunked) ---------
// R4: split ic into 2 chunks of 32 -> A planes [18][18][32] (LDS 47 KB, 2 blocks/CU
// so block B's conv1 VALU overlaps block A's MFMA). Per chunk: conv1 (32 oc) ->
// barrier -> 18 MFMA K-steps accumulating into the same acc. Swizzle: slot
// (icq ^ ((r>>1)&3)) gives even bank spread for 64-B rows (min-cycle b128 ops).
__global__ __launch_bounds__(512, 4) void k_patch(const void* __restrict__ img,
                                                  const float* __restrict__ ws,
                                                  float* __restrict__ feats)
{
  __shared__ __align__(16) ushortb Ahi[18 * 18 * 32];  // 20736 B
  __shared__ __align__(16) ushortb Alo[18 * 18 * 32];  // 20736 B
  __shared__ float timg[768];      // 3KB input tile [3 c][256 px]
  __shared__ float pool4[512];     // per-M-group pooled partials [4 mg][128 oc]
  __shared__ float pm[128];        // pooled mean
  const int F = ((const int*)(ws + O_FLAG))[0];
  const float* W1 = ws + O_W1;  const float* B1 = ws + O_B1;
  const float* FCW = ws + O_FCW; const float* FCB = ws + O_FCB;
  const s16x8* BF = (const s16x8*)(ws + O_W2);   // fragment-major B

  int blk = blockIdx.x; int b = blk >> 10; int pidx = blk & 1023;
  int ph = pidx >> 5, pw = pidx & 31;
  int tid = threadIdx.x;

  // stage input tile (16x16x3) into LDS
  if (tid < 256){
    int y = tid >> 4, x = tid & 15;
    #pragma unroll
    for (int c = 0; c < 3; c++)
      timg[c * 256 + tid] =
        ldin(img, (((size_t)b * 3 + c) * 512 + (ph * 16 + y)) * 512 + (pw * 16 + x), F);
  }
  // zero A boundary rows once (conv1 writes interior only, zeros persist)
  {
    uint4 z4 = make_uint4(0u, 0u, 0u, 0u);
    for (int r = tid; r < 324; r += 512){
      int y = r / 18, x = r - y * 18;
      if (y == 0 || y == 17 || x == 0 || x == 17){
        #pragma unroll
        for (int m = 0; m < 4; m++){
          *(uint4*)&Ahi[r * 32 + m * 8] = z4;
          *(uint4*)&Alo[r * 32 + m * 8] = z4;
        }
      }
    }
  }
  __syncthreads();

  int wv = tid >> 6, ln = tid & 63;
  int mg = wv >> 1, ng = wv & 1;
  int l31 = ln & 31, lhi = ln >> 5;
  int xcol = ln & 15, yrow = l31 >> 4;
  int p = tid & 255, og = tid >> 8;
  int ii = p >> 4, jj = p & 15;

  fx16 acc[2][2];
  #pragma unroll
  for (int m = 0; m < 2; m++)
    #pragma unroll
    for (int n = 0; n < 2; n++)
      #pragma unroll
      for (int r = 0; r < 16; r++) acc[m][n][r] = 0.f;

#define LDFRAG(S, FA, FB) { \
    int sl = (S); if (sl > 17) sl = 17; \
    int tap = sl >> 1, ksub = sl & 1; \
    int dyq = tap / 3, dxq = tap - dyq * 3; \
    int icq0 = ksub * 2 + lhi; \
    { int r_ = (mg * 4 + yrow + dyq) * 18 + xcol + dxq; \
      int idx = r_ * 32 + ((icq0 ^ ((r_ >> 1) & 3)) << 3); \
      FA[0][0] = *(const s16x8*)&Ahi[idx]; \
      FA[0][1] = *(const s16x8*)&Alo[idx]; } \
    { int r_ = (mg * 4 + 2 + yrow + dyq) * 18 + xcol + dxq; \
      int idx = r_ * 32 + ((icq0 ^ ((r_ >> 1) & 3)) << 3); \
      FA[1][0] = *(const s16x8*)&Ahi[idx]; \
      FA[1][1] = *(const s16x8*)&Alo[idx]; } \
    { int cb = ((cbase + sl) * 4 + ng * 2) * 2; \
      FB[0][0] = BF[cb * 64 + ln]; \
      FB[0][1] = BF[cb * 64 + 64 + ln]; \
      FB[1][0] = BF[cb * 64 + 128 + ln]; \
      FB[1][1] = BF[cb * 64 + 192 + ln]; } \
  }

#define MSTEP(FA, FB) { \
    acc[0][0] = __builtin_amdgcn_mfma_f32_32x32x16_bf16(FA[0][0], FB[0][0], acc[0][0], 0, 0, 0); \
    acc[0][1] = __builtin_amdgcn_mfma_f32_32x32x16_bf16(FA[0][0], FB[1][0], acc[0][1], 0, 0, 0); \
    acc[1][0] = __builtin_amdgcn_mfma_f32_32x32x16_bf16(FA[1][0], FB[0][0], acc[1][0], 0, 0, 0); \
    acc[1][1] = __builtin_amdgcn_mfma_f32_32x32x16_bf16(FA[1][0], FB[1][0], acc[1][1], 0, 0, 0); \
    acc[0][0] = __builtin_amdgcn_mfma_f32_32x32x16_bf16(FA[0][1], FB[0][0], acc[0][0], 0, 0, 0); \
    acc[0][1] = __builtin_amdgcn_mfma_f32_32x32x16_bf16(FA[0][1], FB[1][0], acc[0][1], 0, 0, 0); \
    acc[1][0] = __builtin_amdgcn_mfma_f32_32x32x16_bf16(FA[1][1], FB[0][0], acc[1][0], 0, 0, 0); \
    acc[1][1] = __builtin_amdgcn_mfma_f32_32x32x16_bf16(FA[1][1], FB[1][0], acc[1][1], 0, 0, 0); \
    acc[0][0] = __builtin_amdgcn_mfma_f32_32x32x16_bf16(FA[0][0], FB[0][1], acc[0][0], 0, 0, 0); \
    acc[0][1] = __builtin_amdgcn_mfma_f32_32x32x16_bf16(FA[0][0], FB[1][1], acc[0][1], 0, 0, 0); \
    acc[1][0] = __builtin_amdgcn_mfma_f32_32x32x16_bf16(FA[1][0], FB[0][1], acc[1][0], 0, 0, 0); \
    acc[1][1] = __builtin_amdgcn_mfma_f32_32x32x16_bf16(FA[1][0], FB[1][1], acc[1][1], 0, 0, 0); \
  }

  for (int c = 0; c < 2; c++){
    // conv1 chunk c: 32 oc; thread = (pixel p, half og of 16 oc)
    {
      float pin[27];
      #pragma unroll
      for (int cc = 0; cc < 3; cc++)
        #pragma unroll
        for (int dy = 0; dy < 3; dy++)
          #pragma unroll
          for (int dx = 0; dx < 3; dx++){
            int y = ii + dy - 1, x = jj + dx - 1;
            bool ok = (y >= 0 && y < 16 && x >= 0 && x < 16);
            pin[cc * 9 + dy * 3 + dx] = ok ? timg[cc * 256 + y * 16 + x] : 0.f;
          }
      int oc0 = c * 32 + og * 16;
      int w1base = __builtin_amdgcn_readfirstlane(oc0 * 27);
      const float* W1g = W1 + w1base;
      float av[16];
      #pragma unroll
      for (int o = 0; o < 16; o++){
        float a = B1[oc0 + o];
        #pragma unroll
        for (int t = 0; t < 27; t++) a += W1g[o * 27 + t] * pin[t];
        av[o] = gelu_f(a);
      }
      int r = (ii + 1) * 18 + (jj + 1);
      int swz = ((r >> 1) & 3) << 3;
      #pragma unroll
      for (int g = 0; g < 2; g++){
        unsigned int hp[4], lp[4];
        #pragma unroll
        for (int q = 0; q < 4; q++){
          float v0 = av[g * 8 + 2 * q], v1 = av[g * 8 + 2 * q + 1];
          ushortb h0 = f2bf(v0), h1 = f2bf(v1);
          float l0 = v0 - bf2f(h0), l1 = v1 - bf2f(h1);
          hp[q] = (unsigned int)h0 | ((unsigned int)h1 << 16);
          lp[q] = (unsigned int)f2bf(l0) | ((unsigned int)f2bf(l1) << 16);
        }
        int idx = r * 32 + (((og * 2 + g) << 3) ^ swz);
        *(uint4*)&Ahi[idx] = make_uint4(hp[0], hp[1], hp[2], hp[3]);
        *(uint4*)&Alo[idx] = make_uint4(lp[0], lp[1], lp[2], lp[3]);
      }
    }
    __syncthreads();

    // MFMA chunk c: 18 K-steps (9 taps x 2 k-subs of 16), double-buffered
    {
      int cbase = c * 18;
      s16x8 fa0[2][2], fb0[2][2], fa1[2][2], fb1[2][2];
      LDFRAG(0, fa0, fb0);
      for (int s2 = 0; s2 < 9; s2++){
        LDFRAG(2 * s2 + 1, fa1, fb1);
        MSTEP(fa0, fb0);
        LDFRAG(2 * s2 + 2, fa0, fb0);
        MSTEP(fa1, fb1);
      }
    }
    __syncthreads();   // A dead before next chunk's conv1 overwrites it
  }
#undef LDFRAG
#undef MSTEP

  // epilogue: bias + gelu + pool over px. C/D (32x32): col oc = nt*32 + (ln&31),
  // row px-in-tile = (reg&3) + 8*(reg>>2) + 4*(ln>>5). Sum 16 regs x 2 M-tiles
  // per lane, fold the two k-halves (shfl_xor 32), write per-M-group partial.
  #pragma unroll
  for (int n = 0; n < 2; n++){
    int nt = ng * 2 + n;
    float bz = ws[O_B2 + nt * 32 + l31];
    float sum = 0.f;
    #pragma unroll
    for (int m = 0; m < 2; m++)
      #pragma unroll
      for (int r = 0; r < 16; r++)
        sum += gelu_f(acc[m][n][r] + bz);
    sum += __shfl_xor(sum, 32);
    if (lhi == 0) pool4[mg * 128 + nt * 32 + l31] = sum;
  }
  __syncthreads();
  if (tid < 128){
    float sv = pool4[tid] + pool4[128 + tid] + pool4[256 + tid] + pool4[384 + tid];
    pm[tid] = sv * (1.f / 256.f);
  }
  __syncthreads();

  // fc 128 -> 256 (threads 0..255)
  if (tid < 256){
    int df = tid;
    float s = FCB[df];
    const float* wrow = FCW + (size_t)df * 128;
    #pragma unroll
    for (int k = 0; k < 128; k += 4)
      s += wrow[k] * pm[k] + wrow[k + 1] * pm[k + 1]
         + wrow[k + 2] * pm[k + 2] + wrow[k + 3] * pm[k + 3];
    feats[((size_t)(b * 1024 + pidx)) * 256 + df] = s;
  }
}

// ---------------- K3: structure (rsem fused + Boruvka MST + adjacency + level BFS) ---
__device__ __forceinline__ void edge_uv(int e, int& u, int& v){
  if (e < 1953){
    int i = e / 63; int k = e - i * 63;
    if (k < 62){ int j = k >> 1; u = i * 32 + j; v = (k & 1) ? u + 32 : u + 1; }
    else { u = i * 32 + 31; v = u + 32; }
  } else { u = 31 * 32 + (e - 1953); v = u + 1; }
}

__global__ __launch_bounds__(1024) void k_struct(float* __restrict__ ws)
{
  __shared__ float s_ninv[1024];
  __shared__ float s_w[NEDGE];
  __shared__ float s_r[1024];
  __shared__ int   s_comp[1024];
  __shared__ int   s_link[1024];
  __shared__ int   s_link2[1024];
  __shared__ unsigned long long s_best[1024];
  __shared__ unsigned char  s_mst[NEDGE];
  __shared__ unsigned short s_adj[1024 * 4];
  __shared__ unsigned char  s_deg[1024];
  __shared__ unsigned short s_bfs[1024];
  __shared__ short          s_parof[1024];
  __shared__ unsigned short s_o2b[1024];
  __shared__ unsigned short s_cur[1024];
  __shared__ unsigned short s_nxt[1024];
  __shared__ unsigned short s_off[1025];
  __shared__ unsigned short s_loff2[1026];
  __shared__ unsigned long long s_rootkey;
  __shared__ int s_ncomp, s_cursz, s_bfscnt, s_nextsz, s_nlvl;

  int b = blockIdx.x; int tid = threadIdx.x;
  const float* feats = ws + O_FEATS + (size_t)b * NP * DFEAT;

  // norms + fused r_sem + defensive init
  {
    const float4* f4 = (const float4*)(feats + (size_t)tid * 256);
    const float4* g4 = (const float4*)(ws + O_GPROJ + b * 256);
    float d = 0.f, gdot = 0.f;
    for (int k = 0; k < 64; k++){
      float4 q = f4[k]; float4 g = g4[k];
      d += q.x*q.x + q.y*q.y + q.z*q.z + q.w*q.w;
      gdot += q.x*g.x + q.y*g.y + q.z*g.z + q.w*g.w;
    }
    s_ninv[tid] = 1.f / fmaxf(sqrtf(d), 1e-12f);
    float r = 1.f / (1.f + expf(-gdot * (1.f / 16.f)));
    s_r[tid] = r;
    ws[O_RSEM + b * NP + tid] = r;      // k_xdelta consumes this
    s_comp[tid] = tid;
    s_deg[tid] = 0;
    s_bfs[tid] = (unsigned short)tid;
    s_o2b[tid] = (unsigned short)tid;
    s_parof[tid] = -1;
  }
  for (int e = tid; e < NEDGE; e += 1024) s_mst[e] = 0;
  __syncthreads();

  // edge weights
  for (int e = tid; e < NEDGE; e += 1024){
    int u, v; edge_uv(e, u, v);
    const float4* fu = (const float4*)(feats + (size_t)u * 256);
    const float4* fv = (const float4*)(feats + (size_t)v * 256);
    float d = 0.f;
    for (int k = 0; k < 64; k++){ float4 a = fu[k], c = fv[k]; d += a.x*c.x + a.y*c.y + a.z*c.z + a.w*c.w; }
    float cosv = d * s_ninv[u] * s_ninv[v];
    s_w[e] = (1.f - s_r[u]) * (1.f - s_r[v]) * (-cosv) + 1e-6f;
  }
  __syncthreads();

  // Boruvka rounds (root chase instead of fixed pointer-jumping: exact, fewer barriers)
  for (int round = 0; round < 12; round++){
    s_best[tid] = ~0ull;
    __syncthreads();
    for (int e = tid; e < NEDGE; e += 1024){
      int u, v; edge_uv(e, u, v);
      int cu = s_comp[u], cv = s_comp[v];
      if (cu != cv){
        unsigned long long key = (((unsigned long long)f2sort(s_w[e])) << 32) | (unsigned int)e;
        atomicMin(&s_best[cu], key);
        atomicMin(&s_best[cv], key);
      }
    }
    __syncthreads();
    int l = tid;
    if (s_comp[tid] == tid && s_best[tid] != ~0ull){
      int e = (int)(s_best[tid] & 0xffffffffu);
      int u, v; edge_uv(e, u, v);
      s_mst[e] = 1;
      int cu = s_comp[u], cv = s_comp[v];
      l = (cu == tid) ? cv : cu;
    }
    s_link[tid] = l;
    __syncthreads();
    if (l != tid && s_link[l] == tid && tid < l) s_link[tid] = tid; // break 2-cycles
    __syncthreads();
    // chase to root (links static: only 2-cycles existed, now broken -> acyclic)
    {
      int x = tid;
      int p = s_link[x];
      while (p != x){ x = p; p = s_link[x]; }
      s_link2[tid] = x;
    }
    __syncthreads();
    s_comp[tid] = s_link2[s_comp[tid]];
    if (tid == 0) s_ncomp = 0;
    __syncthreads();
    if (s_comp[tid] == tid) atomicAdd(&s_ncomp, 1);
    __syncthreads();
    if (s_ncomp == 1) break;
    __syncthreads();
  }
  __syncthreads();

  // weight-ordered adjacency (== Kruskal insertion order for unique MST)
  {
    int v = tid; int i = v >> 5, j = v & 31;
    float wloc[4]; int nloc[4]; int d = 0;
    if (j > 0){ int e = (i < 31) ? (i * 63 + 2 * (j - 1)) : (1953 + (j - 1));
      if (s_mst[e]){ wloc[d] = s_w[e]; nloc[d] = v - 1; d++; } }
    if (j < 31){ int e = (i < 31) ? (i * 63 + 2 * j) : (1953 + j);
      if (s_mst[e]){ wloc[d] = s_w[e]; nloc[d] = v + 1; d++; } }
    if (i > 0){ int e = (i - 1) * 63 + ((j < 31) ? (2 * j + 1) : 62);
      if (s_mst[e]){ wloc[d] = s_w[e]; nloc[d] = v - 32; d++; } }
    if (i < 31){ int e = i * 63 + ((j < 31) ? (2 * j + 1) : 62);
      if (s_mst[e]){ wloc[d] = s_w[e]; nloc[d] = v + 32; d++; } }
    for (int a = 1; a < d; a++){
      float wv = wloc[a]; int nv = nloc[a]; int c = a - 1;
      while (c >= 0 && wloc[c] > wv){ wloc[c+1] = wloc[c]; nloc[c+1] = nloc[c]; c--; }
      wloc[c+1] = wv; nloc[c+1] = nv;
    }
    s_deg[v] = (unsigned char)d;
    for (int a = 0; a < d; a++) s_adj[v * 4 + a] = (unsigned short)nloc[a];
  }
  // root = argmax r (first index on ties)
  if (tid == 0) s_rootkey = 0ull;
  __syncthreads();
  {
    unsigned long long key = (((unsigned long long)f2sort(s_r[tid])) << 32) | (unsigned int)(1023 - tid);
    atomicMax(&s_rootkey, key);
  }
  __syncthreads();
  int root = 1023 - (int)(s_rootkey & 0xffffffffu);

  // level-parallel tree BFS (records level offsets for k_scan)
  if (tid == 0){
    s_bfs[0] = (unsigned short)root; s_o2b[root] = 0; s_parof[root] = -1;
    s_cur[0] = (unsigned short)root; s_cursz = 1; s_bfscnt = 1; s_nlvl = 0;
  }
  __syncthreads();
  for (int lev = 0; lev < 1024; lev++){
    int csz = s_cursz;
    if (csz <= 0) break;
    // wave-parallel exclusive scan of child counts
    if (tid < 64){
      int runbase = 0;
      for (int t0 = 0; t0 < csz; t0 += 64){
        int t = t0 + tid;
        int cnt = 0;
        if (t < csz){
          int n = s_cur[t];
          cnt = (int)s_deg[n] - (s_parof[n] >= 0 ? 1 : 0);
        }
        int v = cnt;
        #pragma unroll
        for (int off = 1; off < 64; off <<= 1){
          int u2 = __shfl_up(v, off);
          if (tid >= off) v += u2;
        }
        if (t < csz) s_off[t] = (unsigned short)(runbase + v - cnt);
        runbase += __shfl(v, 63);
      }
      if (tid == 0){
        if (s_nlvl < 1025){ s_loff2[s_nlvl] = (unsigned short)(s_bfscnt - csz); }
        s_nlvl++;
        s_nextsz = runbase;
      }
    }
    __syncthreads();
    if (tid < csz){
      int n = s_cur[tid]; int base = s_off[tid]; int k = 0;
      int pn = s_parof[n]; int dg = s_deg[n];
      for (int a = 0; a < dg; a++){
        int c = s_adj[n * 4 + a];
        if (c == pn) continue;
        s_parof[c] = (short)n;
        if (base + k < 1024) s_nxt[base + k] = (unsigned short)c;
        int pos = s_bfscnt + base + k;
        if (pos < 1024){
          s_bfs[pos] = (unsigned short)c;
          s_o2b[c] = (unsigned short)pos;
        }
        k++;
      }
    }
    __syncthreads();
    if (tid == 0){ s_bfscnt += s_nextsz; s_cursz = (s_nextsz > 1024) ? 1024 : s_nextsz; }
    __syncthreads();
    if (tid < s_cursz) s_cur[tid] = s_nxt[tid];
    __syncthreads();
  }
  __syncthreads();

  int* BFSo = (int*)(ws + O_BFS);
  int* PARo = (int*)(ws + O_PAR);
  {
    int node = s_bfs[tid] & 1023;
    BFSo[b * 1024 + tid] = node;
    int p = s_parof[node];
    PARo[b * 1024 + tid] = (p < 0) ? -1 : (int)(s_o2b[p] & 1023);
  }
  // export level table: [nlvl, loff[0..nlvl]] (loff[nlvl] = NP)
  {
    int* LVLo = (int*)(ws + O_LVL) + b * 1040;
    int nl = s_nlvl; if (nl > 1024) nl = 1024;
    if (tid == 0){ LVLo[0] = nl; LVLo[1 + nl] = NP; }
    if (tid < nl) LVLo[1 + tid] = (int)s_loff2[tid];
  }
}

// ---------------- K4: X, delta, Bp, Cp (k-major coalesced weight reads) --------------
__global__ __launch_bounds__(256) void k_xdelta(float* __restrict__ ws)
{
  __shared__ float xs[256];
  int blk = blockIdx.x; int b = blk >> 10, i = blk & 1023; int df = threadIdx.x;
  const int* BFSo = (const int*)(ws + O_BFS);
  int node = BFSo[b * 1024 + i] & 1023;
  float rs = ws[O_RSEM + b * 1024 + node];
  float xv = ws[O_FEATS + ((size_t)(b * 1024 + node)) * 256 + df] + rs * ws[O_GPRIM + b * 256 + df];
  xs[df] = xv;
  ws[O_X + ((size_t)(b * 1024 + i)) * 256 + df] = xv;
  __syncthreads();
  {
    const float* WT = ws + O_WDW;
    float z = ws[O_WDB + df];
    #pragma unroll 8
    for (int k = 0; k < 256; k++)
      z += WT[(size_t)k * 256 + df] * xs[k];
    float sp = fmaxf(z, 0.f) + log1pf(expf(-fabsf(z)));
    ws[O_DELTA + ((size_t)(b * 1024 + i)) * 256 + df] = sp * (1.f + 2.f * rs);
  }
  if (df < 32){
    int s = df & 15;
    const float* WT = ws + ((df < 16) ? O_BWO : O_CWO);   // [k][s]
    float a = ws[((df < 16) ? O_BBO : O_CBO) + s];
    #pragma unroll 8
    for (int k = 0; k < 256; k++) a += WT[k * 16 + s] * xs[k];
    ws[((df < 16) ? O_BP : O_CP) + (size_t)(b * 1024 + i) * 16 + s] = a;
  }
}

// ---------------- K5: tree scan, LEVEL-PARALLEL, 256 threads -------------------------
__global__ __launch_bounds__(256) void k_scan(float* __restrict__ ws)
{
  __shared__ float h[NP * DSTATE];   // 64 KB: h[pos][s]
  __shared__ float xs[NP];
  __shared__ float ds[NP];
  __shared__ int   par_s[NP];
  __shared__ int   bfs_s[NP];
  int blk = blockIdx.x; int b = blk >> 8, f = blk & 255;
  int tid = threadIdx.x;
  int g = tid >> 4, s = tid & 15;
  const int* PARo = (const int*)(ws + O_PAR);
  const int* BFSo = (const int*)(ws + O_BFS);
  const int* LVLo = (const int*)(ws + O_LVL) + b * 1040;
  for (int i = tid; i < NP; i += 256){
    xs[i] = ws[O_X     + ((size_t)(b * NP + i)) * DFEAT + f];
    ds[i] = ws[O_DELTA + ((size_t)(b * NP + i)) * DFEAT + f];
    par_s[i] = PARo[b * NP + i];
    bfs_s[i] = BFSo[b * NP + i] & 1023;
  }
  __syncthreads();

  int nlvl = LVLo[0];
  bool degen = (nlvl < 1 || nlvl > NP);
  if (degen) nlvl = NP;               // fallback: one node per level == serial order

  float Aln = ws[O_AF + f * 16 + s];
  float Dv  = ws[O_DD + f];
  const float* Bp = ws + O_BP + (size_t)b * NP * DSTATE;
  const float* Cp = ws + O_CP + (size_t)b * NP * DSTATE;
  float* Yr = ws + O_YR + (size_t)b * NP * DFEAT;

  for (int l = 0; l < nlvl; l++){
    int o0, o1;
    if (degen){ o0 = l; o1 = l + 1; }
    else {
      o0 = LVLo[1 + l]; o1 = LVLo[2 + l];
      o0 = (o0 < 0) ? 0 : ((o0 > NP) ? NP : o0);
      o1 = (o1 < o0) ? o0 : ((o1 > NP) ? NP : o1);
    }
    for (int i = o0 + g; i < o1; i += 16){
      int p = par_s[i];
      float d = ds[i], x = xs[i];
      float hp = (p >= 0 && p < i) ? h[p * 16 + s] : 0.f;
      float hn = expf(d * Aln) * hp + d * Bp[i * 16 + s] * x;
      h[i * 16 + s] = hn;
      float t = hn * Cp[i * 16 + s];
      t += __shfl_xor(t, 1); t += __shfl_xor(t, 2);
      t += __shfl_xor(t, 4); t += __shfl_xor(t, 8);
      if (s == 0) Yr[(size_t)bfs_s[i] * DFEAT + f] = t + Dv * x;
    }
    __syncthreads();   // orders level l writes vs l+1 reads
  }
}

// ---------------- K6: out GEMM (k-major coalesced) + LayerNorm -> out dtype ----------
__global__ __launch_bounds__(256) void k_outln(const float* __restrict__ ws,
                                               void* __restrict__ out)
{
  __shared__ float yl[256];
  __shared__ float red[8];
  const int F = ((const int*)(ws + O_FLAG))[0];
  int blk = blockIdx.x; int b = blk >> 10, p = blk & 1023; int df = threadIdx.x;
  yl[df] = ws[O_YR + ((size_t)(b * 1024 + p)) * 256 + df];
  __syncthreads();
  const float* OT = ws + O_OW;   // [k][df]
  float a = ws[O_OB + df];
  #pragma unroll 8
  for (int k = 0; k < 256; k++)
    a += OT[(size_t)k * 256 + df] * yl[k];
  int lane = df & 63, wid = df >> 6;
  float t = a;
  t += __shfl_xor(t, 1); t += __shfl_xor(t, 2);  t += __shfl_xor(t, 4);
  t += __shfl_xor(t, 8); t += __shfl_xor(t, 16); t += __shfl_xor(t, 32);
  if (lane == 0) red[wid] = t;
  __syncthreads();
  float mu = (red[0] + red[1] + red[2] + red[3]) * (1.f / 256.f);
  float dv = a - mu;
  float t2 = dv * dv;
  t2 += __shfl_xor(t2, 1); t2 += __shfl_xor(t2, 2);  t2 += __shfl_xor(t2, 4);
  t2 += __shfl_xor(t2, 8); t2 += __shfl_xor(t2, 16); t2 += __shfl_xor(t2, 32);
  if (lane == 0) red[4 + wid] = t2;
  __syncthreads();
  float var = (red[4] + red[5] + red[6] + red[7]) * (1.f / 256.f);
  float o = ws[O_LNG + df] * dv / sqrtf(var + 1e-5f) + ws[O_LNB + df];
  size_t idx = ((size_t)(b * 1024 + p)) * 256 + df;
  if (F) ((ushortb*)out)[idx] = f2bf(o);
  else   ((float*)out)[idx]   = o;
}

// ---------------- launch ----------------
extern "C" void kernel_launch(void* const* d_in, const int* in_sizes, int n_in,
                              void* d_out, int out_size, void* d_ws, size_t ws_size,
                              hipStream_t stream)
{
  (void)in_sizes; (void)n_in; (void)out_size; (void)ws_size;
  const void* img   = d_in[0];
  const void* lang  = d_in[1];
  const void* c1w   = d_in[2];
  const void* c1b   = d_in[3];
  const void* c2w   = d_in[4];
  const void* c2b   = d_in[5];
  const void* fcw   = d_in[6];
  const void* fcb   = d_in[7];
  const void* wgate = d_in[8];
  const void* wgp   = d_in[9];
  const void* alog  = d_in[10];
  const void* dvec  = d_in[11];
  const void* bw    = d_in[12];
  const void* bb    = d_in[13];
  const void* cw    = d_in[14];
  const void* cb    = d_in[15];
  const void* wdw   = d_in[16];
  const void* wdb   = d_in[17];
  const void* ow    = d_in[18];
  const void* ob    = d_in[19];
  const void* lng   = d_in[20];
  const void* lnb   = d_in[21];
  float* ws = (float*)d_ws;

  k_sniff<<<1, 256, 0, stream>>>(img, ws);
  k_convert<<<990 + 2048 + 256, 256, 0, stream>>>(c1w, c1b, c2w, c2b, fcw, fcb, alog, dvec,
                                                  bw, bb, cw, cb, wdw, wdb, ow, ob, lng, lnb,
                                                  lang, wgate, wgp, ws);
  k_patch<<<2048, 512, 0, stream>>>(img, ws, ws + O_FEATS);
  k_struct<<<2, 1024, 0, stream>>>(ws);
  k_xdelta<<<2048, 256, 0, stream>>>(ws);
  k_scan<<<NB * DFEAT, 256, 0, stream>>>(ws);
  k_outln<<<2048, 256, 0, stream>>>(ws, d_out);
}

// Round 5
// 885.965 us; speedup vs baseline: 1.4844x; 1.4844x over previous
//
#include <hip/hip_runtime.h>
#include <cstddef>
#include <cstdint>

// ---------------- constants ----------------
#define NB    2
#define NP    1024    // patches per image
#define DFEAT 256
#define DSTATE 16
#define NEDGE 1984    // grid edges: 31*63 + 31

typedef unsigned short ushortb;

// MFMA fragment types (gfx950 32x32x16 bf16)
typedef float fx16 __attribute__((ext_vector_type(16)));
typedef short s16x8 __attribute__((ext_vector_type(8)));

// ---------------- helpers ----------------
__device__ __forceinline__ float bf2f(unsigned short u){
  union { unsigned int i; float f; } c; c.i = ((unsigned int)u) << 16; return c.f;
}
__device__ __forceinline__ unsigned short f2bf(float f){
  union { float f; unsigned int i; } c; c.f = f;
  unsigned int u = c.i;
  unsigned int r = (u + 0x7fffu + ((u >> 16) & 1u)) >> 16;
  return (unsigned short)r;
}
// dtype-generic input load: isbf ? bf16[i] : fp32[i]
__device__ __forceinline__ float ldin(const void* p, size_t i, int isbf){
  return isbf ? bf2f(((const ushortb*)p)[i]) : ((const float*)p)[i];
}
__device__ __forceinline__ float gelu_f(float x){
  return 0.5f * x * (1.0f + erff(x * 0.70710678118654752f));
}
__device__ __forceinline__ unsigned int f2sort(float f){
  union { float f; unsigned int i; } c; c.f = f;
  return (c.i & 0x80000000u) ? ~c.i : (c.i | 0x80000000u);
}

// ---------------- ws layout (float element offsets) ----------------
constexpr size_t AL(size_t x){ return (x + 63) & ~(size_t)63; }
constexpr size_t O_W1    = 0;                       // 1728  conv1 w fp32
constexpr size_t O_B1    = AL(O_W1 + 1728);         // 64
constexpr size_t O_W2    = AL(O_B1 + 64);           // 73728 floats = 147456 bf16, FRAGMENT-MAJOR
                                                    //   chunked for K-split: sg = c*18 + tap*2 + ksub
constexpr size_t O_B2    = AL(O_W2 + 73728);        // 128
constexpr size_t O_FCW   = AL(O_B2 + 128);          // 32768 [df][128]
constexpr size_t O_FCB   = AL(O_FCW + 32768);       // 256
constexpr size_t O_WDW   = AL(O_FCB + 256);         // 65536 TRANSPOSED [k][df]
constexpr size_t O_WDB   = AL(O_WDW + 65536);       // 256
constexpr size_t O_BWO   = AL(O_WDB + 256);         // 4096 TRANSPOSED [k][s]
constexpr size_t O_BBO   = AL(O_BWO + 4096);        // 16
constexpr size_t O_CWO   = AL(O_BBO + 16);          // 4096 TRANSPOSED [k][s]
constexpr size_t O_CBO   = AL(O_CWO + 4096);        // 16
constexpr size_t O_OW    = AL(O_CBO + 16);          // 65536 TRANSPOSED [k][df]
constexpr size_t O_OB    = AL(O_OW + 65536);        // 256
constexpr size_t O_AF    = AL(O_OB + 256);          // 4096  A = -exp(A_log), [f][s]
constexpr size_t O_DD    = AL(O_AF + 4096);         // 256
constexpr size_t O_LNG   = AL(O_DD + 256);          // 256
constexpr size_t O_LNB   = AL(O_LNG + 256);         // 256
constexpr size_t O_FEATS = AL(O_LNB + 256);         // 2*1024*256
constexpr size_t O_GPROJ = AL(O_FEATS + (size_t)NB*NP*DFEAT); // 512
constexpr size_t O_GPRIM = AL(O_GPROJ + NB*DFEAT);  // 512
constexpr size_t O_RSEM  = AL(O_GPRIM + NB*DFEAT);  // 2048
constexpr size_t O_BFS   = AL(O_RSEM + NB*NP);      // 2048 (int)
constexpr size_t O_PAR   = AL(O_BFS + NB*NP);       // 2048 (int)
constexpr size_t O_X     = AL(O_PAR + NB*NP);       // 2*1024*256
constexpr size_t O_DELTA = AL(O_X + (size_t)NB*NP*DFEAT);
constexpr size_t O_BP    = AL(O_DELTA + (size_t)NB*NP*DFEAT); // 2*1024*16
constexpr size_t O_CP    = AL(O_BP + NB*NP*DSTATE);
constexpr size_t O_YR    = AL(O_CP + NB*NP*DSTATE); // 2*1024*256
constexpr size_t O_FLAG  = AL(O_YR + (size_t)NB*NP*DFEAT);    // 1 int: is-bf16 flag
constexpr size_t O_LVL   = AL(O_FLAG + 64);         // NB*1040 ints: [nlvl, loff[0..nlvl]]

// ---------------- K-1: sniff input dtype (bf16 vs fp32) from images buffer -----------
__global__ __launch_bounds__(256) void k_sniff(const void* img, float* ws)
{
  __shared__ int cnt;
  int tid = threadIdx.x;
  if (tid == 0) cnt = 0;
  __syncthreads();
  const ushortb* u = (const ushortb*)img;
  int local = 0;
  for (int k = 0; k < 16; k++){
    unsigned short v = u[tid * 16 + k];
    if (v == 0 || v == 0x8000u){ local++; continue; }
    float f = fabsf(bf2f(v));
    if (f >= 1e-8f && f <= 64.f) local++;    // plausible N(0,1) bf16
  }
  atomicAdd(&cnt, local);
  __syncthreads();
  if (tid == 0) ((int*)(ws + O_FLAG))[0] = (cnt >= 3900) ? 1 : 0;  // >=95% plausible
}

// ---------------- K0: convert weights + zero YR + g_proj/g_prime (all fused) ---------
// blocks [0,990): weight convert; [990,3038): YR zero; [3038,3294): gmm rows.
__global__ __launch_bounds__(256) void k_convert(const void* c1w, const void* c1b, const void* c2w,
                          const void* c2b, const void* fcw, const void* fcb,
                          const void* alog, const void* dvec,
                          const void* bw, const void* bb, const void* cw, const void* cb,
                          const void* wdw, const void* wdb,
                          const void* ow, const void* ob,
                          const void* lng, const void* lnb,
                          const void* lang, const void* wgate, const void* wgp,
                          float* ws)
{
  const int F = ((const int*)(ws + O_FLAG))[0];
  if (blockIdx.x >= 3038){  // gmm branch: wave-per-row coalesced dual GEMV
    int row = (blockIdx.x - 3038) * 4 + (threadIdx.x >> 6);
    int lane = threadIdx.x & 63;
    int mat = row >> 9;
    int b   = (row >> 8) & 1;
    int df  = row & 255;
    const void* W = mat ? wgp : wgate;
    float s = 0.f;
    for (int k = lane; k < 896; k += 64)
      s += ldin(lang, (size_t)b * 896 + k, F) * ldin(W, (size_t)df * 896 + k, F);
    s += __shfl_xor(s, 1);  s += __shfl_xor(s, 2);  s += __shfl_xor(s, 4);
    s += __shfl_xor(s, 8);  s += __shfl_xor(s, 16); s += __shfl_xor(s, 32);
    if (lane == 0) ws[(mat ? O_GPRIM : O_GPROJ) + b * 256 + df] = s;
    return;
  }
  if (blockIdx.x >= 990){   // init branch: zero YR
    size_t i2 = (size_t)(blockIdx.x - 990) * 256 + threadIdx.x;
    if (i2 < (size_t)NB * NP * DFEAT) ws[O_YR + i2] = 0.f;
    return;
  }
  int i = blockIdx.x * 256 + threadIdx.x;
  if (i < 1728){ ws[O_W1 + i] = ldin(c1w, i, F); return; } i -= 1728;
  if (i < 64){ ws[O_B1 + i] = ldin(c1b, i, F); return; } i -= 64;
  if (i < 73728){
    // fragment-major bf16-split conv2 weights for chunked 32x32x16 MFMA.
    // step sg = c*18 + tap*2 + ksub (c = ic chunk of 32).
    // lane ln holds oc = nt*32 + (ln&31), k-in-step = (ln>>5)*8 + e.
    int sg = i >> 11;           // 0..35
    int r = i & 2047;
    int nt = r >> 9;
    int r2 = r & 511;           // ln*8 + e
    int ln = r2 >> 3, e = r2 & 7;
    int c  = sg / 18, s = sg - c * 18;
    int tap = s >> 1, ksub = s & 1;
    int oc = nt * 32 + (ln & 31);
    int ic = c * 32 + ksub * 16 + (ln >> 5) * 8 + e;
    float v = ldin(c2w, (size_t)(oc * 64 + ic) * 9 + tap, F);
    ushortb hi = f2bf(v);
    float lo = v - bf2f(hi);
    ushortb* WB = (ushortb*)(ws + O_W2);
    size_t cb = ((size_t)(sg * 4 + nt)) * 2;
    WB[cb * 512 + r2]       = hi;         // plane 0
    WB[(cb + 1) * 512 + r2] = f2bf(lo);   // plane 1
    return;
  } i -= 73728;
  if (i < 128){ ws[O_B2 + i] = ldin(c2b, i, F); return; } i -= 128;
  if (i < 32768){ ws[O_FCW + i] = ldin(fcw, i, F); return; } i -= 32768;
  if (i < 256){ ws[O_FCB + i] = ldin(fcb, i, F); return; } i -= 256;
  if (i < 65536){  // WDW transposed: dst[k*256+df] = src[df*256+k]
    int k = i >> 8, df = i & 255;
    ws[O_WDW + i] = ldin(wdw, (size_t)df * 256 + k, F); return;
  } i -= 65536;
  if (i < 256){ ws[O_WDB + i] = ldin(wdb, i, F); return; } i -= 256;
  if (i < 4096){   // B_w transposed: dst[k*16+s] = src[s*256+k]
    int k = i >> 4, s = i & 15;
    ws[O_BWO + i] = ldin(bw, (size_t)s * 256 + k, F); return;
  } i -= 4096;
  if (i < 16){ ws[O_BBO + i] = ldin(bb, i, F); return; } i -= 16;
  if (i < 4096){   // C_w transposed
    int k = i >> 4, s = i & 15;
    ws[O_CWO + i] = ldin(cw, (size_t)s * 256 + k, F); return;
  } i -= 4096;
  if (i < 16){ ws[O_CBO + i] = ldin(cb, i, F); return; } i -= 16;
  if (i < 65536){  // out_w transposed: dst[k*256+df] = src[df*256+k]
    int k = i >> 8, df = i & 255;
    ws[O_OW + i] = ldin(ow, (size_t)df * 256 + k, F); return;
  } i -= 65536;
  if (i < 256){ ws[O_OB + i] = ldin(ob, i, F); return; } i -= 256;
  if (i < 4096){ ws[O_AF + i] = -expf(ldin(alog, i, F)); return; } i -= 4096;
  if (i < 256){ ws[O_DD + i] = ldin(dvec, i, F); return; } i -= 256;
  if (i < 256){ ws[O_LNG + i] = ldin(lng, i, F); return; } i -= 256;
  if (i < 256){ ws[O_LNB + i] = ldin(lnb, i, F); }
}

// ---------------- K1: per-patch conv1 + MFMA conv2 (bf16 3-split, K-chunked) ---------
// R5: fit the 128-reg budget of __launch_bounds__(512,4) (R4 spilled: 956 MB scratch
// writes). Single-buffered fragments (8 x s16x8 = 32 VGPR), conv1 in 8-oc slices
// (av[8]), merged hi/lo LDS plane (constant 20736 B offset). acc = 64 AGPR.
// Peak ~120 regs -> no spill, 2 blocks/CU (LDS 47 KB): block B conv1 VALU overlaps
// block A MFMA. Accumulation order bitwise identical to R3/R4.
__global__ __launch_bounds__(512, 4) void k_patch(const void* __restrict__ img,
                                                  const float* __restrict__ ws,
                                                  float* __restrict__ feats)
{
  __shared__ __align__(16) ushortb Abuf[2 * 10368];  // hi plane [0], lo plane [10368]
  __shared__ float timg[768];      // 3KB input tile [3 c][256 px]
  __shared__ float pool4[512];     // per-M-group pooled partials [4 mg][128 oc]
  __shared__ float pm[128];        // pooled mean
  const int F = ((const int*)(ws + O_FLAG))[0];
  const float* W1 = ws + O_W1;  const float* B1 = ws + O_B1;
  const float* FCW = ws + O_FCW; const float* FCB = ws + O_FCB;
  const s16x8* BF = (const s16x8*)(ws + O_W2);   // fragment-major B

  int blk = blockIdx.x; int b = blk >> 10; int pidx = blk & 1023;
  int ph = pidx >> 5, pw = pidx & 31;
  int tid = threadIdx.x;

  // stage input tile (16x16x3) into LDS
  if (tid < 256){
    int y = tid >> 4, x = tid & 15;
    #pragma unroll
    for (int c = 0; c < 3; c++)
      timg[c * 256 + tid] =
        ldin(img, (((size_t)b * 3 + c) * 512 + (ph * 16 + y)) * 512 + (pw * 16 + x), F);
  }
  // zero A boundary rows once (conv1 writes interior only, zeros persist)
  {
    uint4 z4 = make_uint4(0u, 0u, 0u, 0u);
    for (int r = tid; r < 324; r += 512){
      int y = r / 18, x = r - y * 18;
      if (y == 0 || y == 17 || x == 0 || x == 17){
        #pragma unroll
        for (int m = 0; m < 4; m++){
          *(uint4*)&Abuf[r * 32 + m * 8] = z4;
          *(uint4*)&Abuf[10368 + r * 32 + m * 8] = z4;
        }
      }
    }
  }
  __syncthreads();

  int wv = tid >> 6, ln = tid & 63;
  int mg = wv >> 1, ng = wv & 1;
  int l31 = ln & 31, lhi = ln >> 5;
  int xcol = ln & 15, yrow = l31 >> 4;
  int p = tid & 255, og = tid >> 8;
  int ii = p >> 4, jj = p & 15;

  fx16 acc00, acc01, acc10, acc11;
  #pragma unroll
  for (int r = 0; r < 16; r++){ acc00[r] = 0.f; acc01[r] = 0.f; acc10[r] = 0.f; acc11[r] = 0.f; }

  for (int c = 0; c < 2; c++){
    // conv1 chunk c: 32 oc; thread = (pixel p, half og of 16 oc), 8-oc slices
    {
      float pin[27];
      #pragma unroll
      for (int cc = 0; cc < 3; cc++)
        #pragma unroll
        for (int dy = 0; dy < 3; dy++)
          #pragma unroll
          for (int dx = 0; dx < 3; dx++){
            int y = ii + dy - 1, x = jj + dx - 1;
            bool ok = (y >= 0 && y < 16 && x >= 0 && x < 16);
            pin[cc * 9 + dy * 3 + dx] = ok ? timg[cc * 256 + y * 16 + x] : 0.f;
          }
      int oc0 = c * 32 + og * 16;
      int w1base = __builtin_amdgcn_readfirstlane(oc0 * 27);
      const float* W1g = W1 + w1base;
      int r = (ii + 1) * 18 + (jj + 1);
      int swz = ((r >> 1) & 3) << 3;
      #pragma unroll
      for (int g = 0; g < 2; g++){
        float av[8];
        #pragma unroll
        for (int o = 0; o < 8; o++){
          float a = B1[oc0 + g * 8 + o];
          #pragma unroll
          for (int t = 0; t < 27; t++) a += W1g[(g * 8 + o) * 27 + t] * pin[t];
          av[o] = gelu_f(a);
        }
        unsigned int hp[4], lp[4];
        #pragma unroll
        for (int q = 0; q < 4; q++){
          float v0 = av[2 * q], v1 = av[2 * q + 1];
          ushortb h0 = f2bf(v0), h1 = f2bf(v1);
          float l0 = v0 - bf2f(h0), l1 = v1 - bf2f(h1);
          hp[q] = (unsigned int)h0 | ((unsigned int)h1 << 16);
          lp[q] = (unsigned int)f2bf(l0) | ((unsigned int)f2bf(l1) << 16);
        }
        int idx = r * 32 + (((og * 2 + g) << 3) ^ swz);
        *(uint4*)&Abuf[idx] = make_uint4(hp[0], hp[1], hp[2], hp[3]);
        *(uint4*)&Abuf[10368 + idx] = make_uint4(lp[0], lp[1], lp[2], lp[3]);
      }
    }
    __syncthreads();

    // MFMA chunk c: 18 K-steps (9 taps x 2 k-subs of 16), single-buffered frags
    {
      const s16x8* bfp = BF + (size_t)((c * 144 + ng * 4) * 64 + ln);
      for (int s = 0; s < 18; s++){
        int tap = s >> 1, ksub = s & 1;
        int dyq = tap / 3, dxq = tap - dyq * 3;
        int icq0 = (ksub << 1) + lhi;                 // 8-ic group 0..3
        int rA = (mg * 4 + yrow + dyq) * 18 + (xcol + dxq);
        int rB = rA + 36;                             // +2 rows
        int iA0 = rA * 32 + ((icq0 ^ ((rA >> 1) & 3)) << 3);
        int iA1 = rB * 32 + ((icq0 ^ ((rB >> 1) & 3)) << 3);
        s16x8 fa0h = *(const s16x8*)&Abuf[iA0];
        s16x8 fa0l = *(const s16x8*)&Abuf[10368 + iA0];
        s16x8 fa1h = *(const s16x8*)&Abuf[iA1];
        s16x8 fa1l = *(const s16x8*)&Abuf[10368 + iA1];
        const s16x8* bq = bfp + (s << 9);
        s16x8 fb0h = bq[0];
        s16x8 fb0l = bq[64];
        s16x8 fb1h = bq[128];
        s16x8 fb1l = bq[192];
        acc00 = __builtin_amdgcn_mfma_f32_32x32x16_bf16(fa0h, fb0h, acc00, 0, 0, 0);
        acc01 = __builtin_amdgcn_mfma_f32_32x32x16_bf16(fa0h, fb1h, acc01, 0, 0, 0);
        acc10 = __builtin_amdgcn_mfma_f32_32x32x16_bf16(fa1h, fb0h, acc10, 0, 0, 0);
        acc11 = __builtin_amdgcn_mfma_f32_32x32x16_bf16(fa1h, fb1h, acc11, 0, 0, 0);
        acc00 = __builtin_amdgcn_mfma_f32_32x32x16_bf16(fa0l, fb0h, acc00, 0, 0, 0);
        acc01 = __builtin_amdgcn_mfma_f32_32x32x16_bf16(fa0l, fb1h, acc01, 0, 0, 0);
        acc10 = __builtin_amdgcn_mfma_f32_32x32x16_bf16(fa1l, fb0h, acc10, 0, 0, 0);
        acc11 = __builtin_amdgcn_mfma_f32_32x32x16_bf16(fa1l, fb1h, acc11, 0, 0, 0);
        acc00 = __builtin_amdgcn_mfma_f32_32x32x16_bf16(fa0h, fb0l, acc00, 0, 0, 0);
        acc01 = __builtin_amdgcn_mfma_f32_32x32x16_bf16(fa0h, fb1l, acc01, 0, 0, 0);
        acc10 = __builtin_amdgcn_mfma_f32_32x32x16_bf16(fa1h, fb0l, acc10, 0, 0, 0);
        acc11 = __builtin_amdgcn_mfma_f32_32x32x16_bf16(fa1h, fb1l, acc11, 0, 0, 0);
      }
    }
    __syncthreads();   // A dead before next chunk's conv1 overwrites it
  }

  // epilogue: bias + gelu + pool over px. C/D (32x32): col oc = nt*32 + (ln&31),
  // row px-in-tile = (reg&3) + 8*(reg>>2) + 4*(ln>>5). Sum 16 regs x 2 M-tiles
  // per lane, fold the two k-halves (shfl_xor 32), write per-M-group partial.
  #pragma unroll
  for (int n = 0; n < 2; n++){
    int nt = ng * 2 + n;
    float bz = ws[O_B2 + nt * 32 + l31];
    float sum = 0.f;
    #pragma unroll
    for (int r = 0; r < 16; r++)
      sum += gelu_f(((n == 0) ? acc00[r] : acc01[r]) + bz)
           + gelu_f(((n == 0) ? acc10[r] : acc11[r]) + bz);
    sum += __shfl_xor(sum, 32);
    if (lhi == 0) pool4[mg * 128 + nt * 32 + l31] = sum;
  }
  __syncthreads();
  if (tid < 128){
    float sv = pool4[tid] + pool4[128 + tid] + pool4[256 + tid] + pool4[384 + tid];
    pm[tid] = sv * (1.f / 256.f);
  }
  __syncthreads();

  // fc 128 -> 256 (threads 0..255)
  if (tid < 256){
    int df = tid;
    float s = FCB[df];
    const float* wrow = FCW + (size_t)df * 128;
    #pragma unroll
    for (int k = 0; k < 128; k += 4)
      s += wrow[k] * pm[k] + wrow[k + 1] * pm[k + 1]
         + wrow[k + 2] * pm[k + 2] + wrow[k + 3] * pm[k + 3];
    feats[((size_t)(b * 1024 + pidx)) * 256 + df] = s;
  }
}

// ---------------- K3: structure (rsem fused + Boruvka MST + adjacency + level BFS) ---
__device__ __forceinline__ void edge_uv(int e, int& u, int& v){
  if (e < 1953){
    int i = e / 63; int k = e - i * 63;
    if (k < 62){ int j = k >> 1; u = i * 32 + j; v = (k & 1) ? u + 32 : u + 1; }
    else { u = i * 32 + 31; v = u + 32; }
  } else { u = 31 * 32 + (e - 1953); v = u + 1; }
}

__global__ __launch_bounds__(1024) void k_struct(float* __restrict__ ws)
{
  __shared__ float s_ninv[1024];
  __shared__ float s_w[NEDGE];
  __shared__ float s_r[1024];
  __shared__ int   s_comp[1024];
  __shared__ int   s_link[1024];
  __shared__ int   s_link2[1024];
  __shared__ unsigned long long s_best[1024];
  __shared__ unsigned char  s_mst[NEDGE];
  __shared__ unsigned short s_adj[1024 * 4];
  __shared__ unsigned char  s_deg[1024];
  __shared__ unsigned short s_bfs[1024];
  __shared__ short          s_parof[1024];
  __shared__ unsigned short s_o2b[1024];
  __shared__ unsigned short s_cur[1024];
  __shared__ unsigned short s_nxt[1024];
  __shared__ unsigned short s_off[1025];
  __shared__ unsigned short s_loff2[1026];
  __shared__ unsigned long long s_rootkey;
  __shared__ int s_ncomp, s_cursz, s_bfscnt, s_nextsz, s_nlvl;

  int b = blockIdx.x; int tid = threadIdx.x;
  const float* feats = ws + O_FEATS + (size_t)b * NP * DFEAT;

  // norms + fused r_sem + defensive init
  {
    const float4* f4 = (const float4*)(feats + (size_t)tid * 256);
    const float4* g4 = (const float4*)(ws + O_GPROJ + b * 256);
    float d = 0.f, gdot = 0.f;
    for (int k = 0; k < 64; k++){
      float4 q = f4[k]; float4 g = g4[k];
      d += q.x*q.x + q.y*q.y + q.z*q.z + q.w*q.w;
      gdot += q.x*g.x + q.y*g.y + q.z*g.z + q.w*g.w;
    }
    s_ninv[tid] = 1.f / fmaxf(sqrtf(d), 1e-12f);
    float r = 1.f / (1.f + expf(-gdot * (1.f / 16.f)));
    s_r[tid] = r;
    ws[O_RSEM + b * NP + tid] = r;      // k_xdelta consumes this
    s_comp[tid] = tid;
    s_deg[tid] = 0;
    s_bfs[tid] = (unsigned short)tid;
    s_o2b[tid] = (unsigned short)tid;
    s_parof[tid] = -1;
  }
  for (int e = tid; e < NEDGE; e += 1024) s_mst[e] = 0;
  __syncthreads();

  // edge weights
  for (int e = tid; e < NEDGE; e += 1024){
    int u, v; edge_uv(e, u, v);
    const float4* fu = (const float4*)(feats + (size_t)u * 256);
    const float4* fv = (const float4*)(feats + (size_t)v * 256);
    float d = 0.f;
    for (int k = 0; k < 64; k++){ float4 a = fu[k], c = fv[k]; d += a.x*c.x + a.y*c.y + a.z*c.z + a.w*c.w; }
    float cosv = d * s_ninv[u] * s_ninv[v];
    s_w[e] = (1.f - s_r[u]) * (1.f - s_r[v]) * (-cosv) + 1e-6f;
  }
  __syncthreads();

  // Boruvka rounds (root chase instead of fixed pointer-jumping: exact, fewer barriers)
  for (int round = 0; round < 12; round++){
    s_best[tid] = ~0ull;
    __syncthreads();
    for (int e = tid; e < NEDGE; e += 1024){
      int u, v; edge_uv(e, u, v);
      int cu = s_comp[u], cv = s_comp[v];
      if (cu != cv){
        unsigned long long key = (((unsigned long long)f2sort(s_w[e])) << 32) | (unsigned int)e;
        atomicMin(&s_best[cu], key);
        atomicMin(&s_best[cv], key);
      }
    }
    __syncthreads();
    int l = tid;
    if (s_comp[tid] == tid && s_best[tid] != ~0ull){
      int e = (int)(s_best[tid] & 0xffffffffu);
      int u, v; edge_uv(e, u, v);
      s_mst[e] = 1;
      int cu = s_comp[u], cv = s_comp[v];
      l = (cu == tid) ? cv : cu;
    }
    s_link[tid] = l;
    __syncthreads();
    if (l != tid && s_link[l] == tid && tid < l) s_link[tid] = tid; // break 2-cycles
    __syncthreads();
    // chase to root (links static: only 2-cycles existed, now broken -> acyclic)
    {
      int x = tid;
      int p = s_link[x];
      while (p != x){ x = p; p = s_link[x]; }
      s_link2[tid] = x;
    }
    __syncthreads();
    s_comp[tid] = s_link2[s_comp[tid]];
    if (tid == 0) s_ncomp = 0;
    __syncthreads();
    if (s_comp[tid] == tid) atomicAdd(&s_ncomp, 1);
    __syncthreads();
    if (s_ncomp == 1) break;
    __syncthreads();
  }
  __syncthreads();

  // weight-ordered adjacency (== Kruskal insertion order for unique MST)
  {
    int v = tid; int i = v >> 5, j = v & 31;
    float wloc[4]; int nloc[4]; int d = 0;
    if (j > 0){ int e = (i < 31) ? (i * 63 + 2 * (j - 1)) : (1953 + (j - 1));
      if (s_mst[e]){ wloc[d] = s_w[e]; nloc[d] = v - 1; d++; } }
    if (j < 31){ int e = (i < 31) ? (i * 63 + 2 * j) : (1953 + j);
      if (s_mst[e]){ wloc[d] = s_w[e]; nloc[d] = v + 1; d++; } }
    if (i > 0){ int e = (i - 1) * 63 + ((j < 31) ? (2 * j + 1) : 62);
      if (s_mst[e]){ wloc[d] = s_w[e]; nloc[d] = v - 32; d++; } }
    if (i < 31){ int e = i * 63 + ((j < 31) ? (2 * j + 1) : 62);
      if (s_mst[e]){ wloc[d] = s_w[e]; nloc[d] = v + 32; d++; } }
    for (int a = 1; a < d; a++){
      float wv = wloc[a]; int nv = nloc[a]; int c = a - 1;
      while (c >= 0 && wloc[c] > wv){ wloc[c+1] = wloc[c]; nloc[c+1] = nloc[c]; c--; }
      wloc[c+1] = wv; nloc[c+1] = nv;
    }
    s_deg[v] = (unsigned char)d;
    for (int a = 0; a < d; a++) s_adj[v * 4 + a] = (unsigned short)nloc[a];
  }
  // root = argmax r (first index on ties)
  if (tid == 0) s_rootkey = 0ull;
  __syncthreads();
  {
    unsigned long long key = (((unsigned long long)f2sort(s_r[tid])) << 32) | (unsigned int)(1023 - tid);
    atomicMax(&s_rootkey, key);
  }
  __syncthreads();
  int root = 1023 - (int)(s_rootkey & 0xffffffffu);

  // level-parallel tree BFS (records level offsets for k_scan)
  if (tid == 0){
    s_bfs[0] = (unsigned short)root; s_o2b[root] = 0; s_parof[root] = -1;
    s_cur[0] = (unsigned short)root; s_cursz = 1; s_bfscnt = 1; s_nlvl = 0;
  }
  __syncthreads();
  for (int lev = 0; lev < 1024; lev++){
    int csz = s_cursz;
    if (csz <= 0) break;
    // wave-parallel exclusive scan of child counts
    if (tid < 64){
      int runbase = 0;
      for (int t0 = 0; t0 < csz; t0 += 64){
        int t = t0 + tid;
        int cnt = 0;
        if (t < csz){
          int n = s_cur[t];
          cnt = (int)s_deg[n] - (s_parof[n] >= 0 ? 1 : 0);
        }
        int v = cnt;
        #pragma unroll
        for (int off = 1; off < 64; off <<= 1){
          int u2 = __shfl_up(v, off);
          if (tid >= off) v += u2;
        }
        if (t < csz) s_off[t] = (unsigned short)(runbase + v - cnt);
        runbase += __shfl(v, 63);
      }
      if (tid == 0){
        if (s_nlvl < 1025){ s_loff2[s_nlvl] = (unsigned short)(s_bfscnt - csz); }
        s_nlvl++;
        s_nextsz = runbase;
      }
    }
    __syncthreads();
    if (tid < csz){
      int n = s_cur[tid]; int base = s_off[tid]; int k = 0;
      int pn = s_parof[n]; int dg = s_deg[n];
      for (int a = 0; a < dg; a++){
        int c = s_adj[n * 4 + a];
        if (c == pn) continue;
        s_parof[c] = (short)n;
        if (base + k < 1024) s_nxt[base + k] = (unsigned short)c;
        int pos = s_bfscnt + base + k;
        if (pos < 1024){
          s_bfs[pos] = (unsigned short)c;
          s_o2b[c] = (unsigned short)pos;
        }
        k++;
      }
    }
    __syncthreads();
    if (tid == 0){ s_bfscnt += s_nextsz; s_cursz = (s_nextsz > 1024) ? 1024 : s_nextsz; }
    __syncthreads();
    if (tid < s_cursz) s_cur[tid] = s_nxt[tid];
    __syncthreads();
  }
  __syncthreads();

  int* BFSo = (int*)(ws + O_BFS);
  int* PARo = (int*)(ws + O_PAR);
  {
    int node = s_bfs[tid] & 1023;
    BFSo[b * 1024 + tid] = node;
    int p = s_parof[node];
    PARo[b * 1024 + tid] = (p < 0) ? -1 : (int)(s_o2b[p] & 1023);
  }
  // export level table: [nlvl, loff[0..nlvl]] (loff[nlvl] = NP)
  {
    int* LVLo = (int*)(ws + O_LVL) + b * 1040;
    int nl = s_nlvl; if (nl > 1024) nl = 1024;
    if (tid == 0){ LVLo[0] = nl; LVLo[1 + nl] = NP; }
    if (tid < nl) LVLo[1 + tid] = (int)s_loff2[tid];
  }
}

// ---------------- K4: X, delta, Bp, Cp (k-major coalesced weight reads) --------------
__global__ __launch_bounds__(256) void k_xdelta(float* __restrict__ ws)
{
  __shared__ float xs[256];
  int blk = blockIdx.x; int b = blk >> 10, i = blk & 1023; int df = threadIdx.x;
  const int* BFSo = (const int*)(ws + O_BFS);
  int node = BFSo[b * 1024 + i] & 1023;
  float rs = ws[O_RSEM + b * 1024 + node];
  float xv = ws[O_FEATS + ((size_t)(b * 1024 + node)) * 256 + df] + rs * ws[O_GPRIM + b * 256 + df];
  xs[df] = xv;
  ws[O_X + ((size_t)(b * 1024 + i)) * 256 + df] = xv;
  __syncthreads();
  {
    const float* WT = ws + O_WDW;
    float z = ws[O_WDB + df];
    #pragma unroll 8
    for (int k = 0; k < 256; k++)
      z += WT[(size_t)k * 256 + df] * xs[k];
    float sp = fmaxf(z, 0.f) + log1pf(expf(-fabsf(z)));
    ws[O_DELTA + ((size_t)(b * 1024 + i)) * 256 + df] = sp * (1.f + 2.f * rs);
  }
  if (df < 32){
    int s = df & 15;
    const float* WT = ws + ((df < 16) ? O_BWO : O_CWO);   // [k][s]
    float a = ws[((df < 16) ? O_BBO : O_CBO) + s];
    #pragma unroll 8
    for (int k = 0; k < 256; k++) a += WT[k * 16 + s] * xs[k];
    ws[((df < 16) ? O_BP : O_CP) + (size_t)(b * 1024 + i) * 16 + s] = a;
  }
}

// ---------------- K5: tree scan, LEVEL-PARALLEL, 256 threads -------------------------
__global__ __launch_bounds__(256) void k_scan(float* __restrict__ ws)
{
  __shared__ float h[NP * DSTATE];   // 64 KB: h[pos][s]
  __shared__ float xs[NP];
  __shared__ float ds[NP];
  __shared__ int   par_s[NP];
  __shared__ int   bfs_s[NP];
  int blk = blockIdx.x; int b = blk >> 8, f = blk & 255;
  int tid = threadIdx.x;
  int g = tid >> 4, s = tid & 15;
  const int* PARo = (const int*)(ws + O_PAR);
  const int* BFSo = (const int*)(ws + O_BFS);
  const int* LVLo = (const int*)(ws + O_LVL) + b * 1040;
  for (int i = tid; i < NP; i += 256){
    xs[i] = ws[O_X     + ((size_t)(b * NP + i)) * DFEAT + f];
    ds[i] = ws[O_DELTA + ((size_t)(b * NP + i)) * DFEAT + f];
    par_s[i] = PARo[b * NP + i];
    bfs_s[i] = BFSo[b * NP + i] & 1023;
  }
  __syncthreads();

  int nlvl = LVLo[0];
  bool degen = (nlvl < 1 || nlvl > NP);
  if (degen) nlvl = NP;               // fallback: one node per level == serial order

  float Aln = ws[O_AF + f * 16 + s];
  float Dv  = ws[O_DD + f];
  const float* Bp = ws + O_BP + (size_t)b * NP * DSTATE;
  const float* Cp = ws + O_CP + (size_t)b * NP * DSTATE;
  float* Yr = ws + O_YR + (size_t)b * NP * DFEAT;

  for (int l = 0; l < nlvl; l++){
    int o0, o1;
    if (degen){ o0 = l; o1 = l + 1; }
    else {
      o0 = LVLo[1 + l]; o1 = LVLo[2 + l];
      o0 = (o0 < 0) ? 0 : ((o0 > NP) ? NP : o0);
      o1 = (o1 < o0) ? o0 : ((o1 > NP) ? NP : o1);
    }
    for (int i = o0 + g; i < o1; i += 16){
      int p = par_s[i];
      float d = ds[i], x = xs[i];
      float hp = (p >= 0 && p < i) ? h[p * 16 + s] : 0.f;
      float hn = expf(d * Aln) * hp + d * Bp[i * 16 + s] * x;
      h[i * 16 + s] = hn;
      float t = hn * Cp[i * 16 + s];
      t += __shfl_xor(t, 1); t += __shfl_xor(t, 2);
      t += __shfl_xor(t, 4); t += __shfl_xor(t, 8);
      if (s == 0) Yr[(size_t)bfs_s[i] * DFEAT + f] = t + Dv * x;
    }
    __syncthreads();   // orders level l writes vs l+1 reads
  }
}

// ---------------- K6: out GEMM (k-major coalesced) + LayerNorm -> out dtype ----------
__global__ __launch_bounds__(256) void k_outln(const float* __restrict__ ws,
                                               void* __restrict__ out)
{
  __shared__ float yl[256];
  __shared__ float red[8];
  const int F = ((const int*)(ws + O_FLAG))[0];
  int blk = blockIdx.x; int b = blk >> 10, p = blk & 1023; int df = threadIdx.x;
  yl[df] = ws[O_YR + ((size_t)(b * 1024 + p)) * 256 + df];
  __syncthreads();
  const float* OT = ws + O_OW;   // [k][df]
  float a = ws[O_OB + df];
  #pragma unroll 8
  for (int k = 0; k < 256; k++)
    a += OT[(size_t)k * 256 + df] * yl[k];
  int lane = df & 63, wid = df >> 6;
  float t = a;
  t += __shfl_xor(t, 1); t += __shfl_xor(t, 2);  t += __shfl_xor(t, 4);
  t += __shfl_xor(t, 8); t += __shfl_xor(t, 16); t += __shfl_xor(t, 32);
  if (lane == 0) red[wid] = t;
  __syncthreads();
  float mu = (red[0] + red[1] + red[2] + red[3]) * (1.f / 256.f);
  float dv = a - mu;
  float t2 = dv * dv;
  t2 += __shfl_xor(t2, 1); t2 += __shfl_xor(t2, 2);  t2 += __shfl_xor(t2, 4);
  t2 += __shfl_xor(t2, 8); t2 += __shfl_xor(t2, 16); t2 += __shfl_xor(t2, 32);
  if (lane == 0) red[4 + wid] = t2;
  __syncthreads();
  float var = (red[4] + red[5] + red[6] + red[7]) * (1.f / 256.f);
  float o = ws[O_LNG + df] * dv / sqrtf(var + 1e-5f) + ws[O_LNB + df];
  size_t idx = ((size_t)(b * 1024 + p)) * 256 + df;
  if (F) ((ushortb*)out)[idx] = f2bf(o);
  else   ((float*)out)[idx]   = o;
}

// ---------------- launch ----------------
extern "C" void kernel_launch(void* const* d_in, const int* in_sizes, int n_in,
                              void* d_out, int out_size, void* d_ws, size_t ws_size,
                              hipStream_t stream)
{
  (void)in_sizes; (void)n_in; (void)out_size; (void)ws_size;
  const void* img   = d_in[0];
  const void* lang  = d_in[1];
  const void* c1w   = d_in[2];
  const void* c1b   = d_in[3];
  const void* c2w   = d_in[4];
  const void* c2b   = d_in[5];
  const void* fcw   = d_in[6];
  const void* fcb   = d_in[7];
  const void* wgate = d_in[8];
  const void* wgp   = d_in[9];
  const void* alog  = d_in[10];
  const void* dvec  = d_in[11];
  const void* bw    = d_in[12];
  const void* bb    = d_in[13];
  const void* cw    = d_in[14];
  const void* cb    = d_in[15];
  const void* wdw   = d_in[16];
  const void* wdb   = d_in[17];
  const void* ow    = d_in[18];
  const void* ob    = d_in[19];
  const void* lng   = d_in[20];
  const void* lnb   = d_in[21];
  float* ws = (float*)d_ws;

  k_sniff<<<1, 256, 0, stream>>>(img, ws);
  k_convert<<<990 + 2048 + 256, 256, 0, stream>>>(c1w, c1b, c2w, c2b, fcw, fcb, alog, dvec,
                                                  bw, bb, cw, cb, wdw, wdb, ow, ob, lng, lnb,
                                                  lang, wgate, wgp, ws);
  k_patch<<<2048, 512, 0, stream>>>(img, ws, ws + O_FEATS);
  k_struct<<<2, 1024, 0, stream>>>(ws);
  k_xdelta<<<2048, 256, 0, stream>>>(ws);
  k_scan<<<NB * DFEAT, 256, 0, stream>>>(ws);
  k_outln<<<2048, 256, 0, stream>>>(ws, d_out);
}

// Round 6
// 868.591 us; speedup vs baseline: 1.5141x; 1.0200x over previous
//
#include <hip/hip_runtime.h>
#include <cstddef>
#include <cstdint>

// ---------------- constants ----------------
#define NB    2
#define NP    1024    // patches per image
#define DFEAT 256
#define DSTATE 16
#define NEDGE 1984    // grid edges: 31*63 + 31

typedef unsigned short ushortb;

// MFMA fragment types (gfx950 32x32x16 bf16)
typedef float fx16 __attribute__((ext_vector_type(16)));
typedef short s16x8 __attribute__((ext_vector_type(8)));

// ---------------- helpers ----------------
__device__ __forceinline__ float bf2f(unsigned short u){
  union { unsigned int i; float f; } c; c.i = ((unsigned int)u) << 16; return c.f;
}
__device__ __forceinline__ unsigned short f2bf(float f){
  union { float f; unsigned int i; } c; c.f = f;
  unsigned int u = c.i;
  unsigned int r = (u + 0x7fffu + ((u >> 16) & 1u)) >> 16;
  return (unsigned short)r;
}
// dtype-generic input load: isbf ? bf16[i] : fp32[i]
__device__ __forceinline__ float ldin(const void* p, size_t i, int isbf){
  return isbf ? bf2f(((const ushortb*)p)[i]) : ((const float*)p)[i];
}
__device__ __forceinline__ float gelu_f(float x){
  return 0.5f * x * (1.0f + erff(x * 0.70710678118654752f));
}
__device__ __forceinline__ unsigned int f2sort(float f){
  union { float f; unsigned int i; } c; c.f = f;
  return (c.i & 0x80000000u) ? ~c.i : (c.i | 0x80000000u);
}

// ---------------- ws layout (float element offsets) ----------------
constexpr size_t AL(size_t x){ return (x + 63) & ~(size_t)63; }
constexpr size_t O_W1    = 0;                       // 1728  conv1 w fp32
constexpr size_t O_B1    = AL(O_W1 + 1728);         // 64
constexpr size_t O_W2    = AL(O_B1 + 64);           // 73728 floats = 147456 bf16, FRAGMENT-MAJOR
                                                    //   chunked for K-split: sg = c*18 + tap*2 + ksub
constexpr size_t O_B2    = AL(O_W2 + 73728);        // 128
constexpr size_t O_FCW   = AL(O_B2 + 128);          // 32768 [df][128]
constexpr size_t O_FCB   = AL(O_FCW + 32768);       // 256
constexpr size_t O_WDW   = AL(O_FCB + 256);         // 65536 TRANSPOSED [k][df]
constexpr size_t O_WDB   = AL(O_WDW + 65536);       // 256
constexpr size_t O_BWO   = AL(O_WDB + 256);         // 4096 TRANSPOSED [k][s]
constexpr size_t O_BBO   = AL(O_BWO + 4096);        // 16
constexpr size_t O_CWO   = AL(O_BBO + 16);          // 4096 TRANSPOSED [k][s]
constexpr size_t O_CBO   = AL(O_CWO + 4096);        // 16
constexpr size_t O_OW    = AL(O_CBO + 16);          // 65536 TRANSPOSED [k][df]
constexpr size_t O_OB    = AL(O_OW + 65536);        // 256
constexpr size_t O_AF    = AL(O_OB + 256);          // 4096  A = -exp(A_log), [f][s]
constexpr size_t O_DD    = AL(O_AF + 4096);         // 256
constexpr size_t O_LNG   = AL(O_DD + 256);          // 256
constexpr size_t O_LNB   = AL(O_LNG + 256);         // 256
constexpr size_t O_FEATS = AL(O_LNB + 256);         // 2*1024*256
constexpr size_t O_GPROJ = AL(O_FEATS + (size_t)NB*NP*DFEAT); // 512
constexpr size_t O_GPRIM = AL(O_GPROJ + NB*DFEAT);  // 512
constexpr size_t O_RSEM  = AL(O_GPRIM + NB*DFEAT);  // 2048
constexpr size_t O_BFS   = AL(O_RSEM + NB*NP);      // 2048 (int)
constexpr size_t O_PAR   = AL(O_BFS + NB*NP);       // 2048 (int)
constexpr size_t O_X     = AL(O_PAR + NB*NP);       // 2*1024*256
constexpr size_t O_DELTA = AL(O_X + (size_t)NB*NP*DFEAT);
constexpr size_t O_BP    = AL(O_DELTA + (size_t)NB*NP*DFEAT); // 2*1024*16
constexpr size_t O_CP    = AL(O_BP + NB*NP*DSTATE);
constexpr size_t O_YR    = AL(O_CP + NB*NP*DSTATE); // 2*1024*256
constexpr size_t O_FLAG  = AL(O_YR + (size_t)NB*NP*DFEAT);    // 1 int: is-bf16 flag
constexpr size_t O_LVL   = AL(O_FLAG + 64);         // NB*1040 ints: [nlvl, loff[0..nlvl]]

// ---------------- K-1: sniff input dtype (bf16 vs fp32) from images buffer -----------
__global__ __launch_bounds__(256) void k_sniff(const void* img, float* ws)
{
  __shared__ int cnt;
  int tid = threadIdx.x;
  if (tid == 0) cnt = 0;
  __syncthreads();
  const ushortb* u = (const ushortb*)img;
  int local = 0;
  for (int k = 0; k < 16; k++){
    unsigned short v = u[tid * 16 + k];
    if (v == 0 || v == 0x8000u){ local++; continue; }
    float f = fabsf(bf2f(v));
    if (f >= 1e-8f && f <= 64.f) local++;    // plausible N(0,1) bf16
  }
  atomicAdd(&cnt, local);
  __syncthreads();
  if (tid == 0) ((int*)(ws + O_FLAG))[0] = (cnt >= 3900) ? 1 : 0;  // >=95% plausible
}

// ---------------- K0: convert weights + zero YR + g_proj/g_prime (all fused) ---------
// blocks [0,990): weight convert; [990,3038): YR zero; [3038,3294): gmm rows.
__global__ __launch_bounds__(256) void k_convert(const void* c1w, const void* c1b, const void* c2w,
                          const void* c2b, const void* fcw, const void* fcb,
                          const void* alog, const void* dvec,
                          const void* bw, const void* bb, const void* cw, const void* cb,
                          const void* wdw, const void* wdb,
                          const void* ow, const void* ob,
                          const void* lng, const void* lnb,
                          const void* lang, const void* wgate, const void* wgp,
                          float* ws)
{
  const int F = ((const int*)(ws + O_FLAG))[0];
  if (blockIdx.x >= 3038){  // gmm branch: wave-per-row coalesced dual GEMV
    int row = (blockIdx.x - 3038) * 4 + (threadIdx.x >> 6);
    int lane = threadIdx.x & 63;
    int mat = row >> 9;
    int b   = (row >> 8) & 1;
    int df  = row & 255;
    const void* W = mat ? wgp : wgate;
    float s = 0.f;
    for (int k = lane; k < 896; k += 64)
      s += ldin(lang, (size_t)b * 896 + k, F) * ldin(W, (size_t)df * 896 + k, F);
    s += __shfl_xor(s, 1);  s += __shfl_xor(s, 2);  s += __shfl_xor(s, 4);
    s += __shfl_xor(s, 8);  s += __shfl_xor(s, 16); s += __shfl_xor(s, 32);
    if (lane == 0) ws[(mat ? O_GPRIM : O_GPROJ) + b * 256 + df] = s;
    return;
  }
  if (blockIdx.x >= 990){   // init branch: zero YR
    size_t i2 = (size_t)(blockIdx.x - 990) * 256 + threadIdx.x;
    if (i2 < (size_t)NB * NP * DFEAT) ws[O_YR + i2] = 0.f;
    return;
  }
  int i = blockIdx.x * 256 + threadIdx.x;
  if (i < 1728){ ws[O_W1 + i] = ldin(c1w, i, F); return; } i -= 1728;
  if (i < 64){ ws[O_B1 + i] = ldin(c1b, i, F); return; } i -= 64;
  if (i < 73728){
    // fragment-major bf16-split conv2 weights for chunked 32x32x16 MFMA.
    // step sg = c*18 + tap*2 + ksub (c = ic chunk of 32).
    // lane ln holds oc = nt*32 + (ln&31), k-in-step = (ln>>5)*8 + e.
    int sg = i >> 11;           // 0..35
    int r = i & 2047;
    int nt = r >> 9;
    int r2 = r & 511;           // ln*8 + e
    int ln = r2 >> 3, e = r2 & 7;
    int c  = sg / 18, s = sg - c * 18;
    int tap = s >> 1, ksub = s & 1;
    int oc = nt * 32 + (ln & 31);
    int ic = c * 32 + ksub * 16 + (ln >> 5) * 8 + e;
    float v = ldin(c2w, (size_t)(oc * 64 + ic) * 9 + tap, F);
    ushortb hi = f2bf(v);
    float lo = v - bf2f(hi);
    ushortb* WB = (ushortb*)(ws + O_W2);
    size_t cb = ((size_t)(sg * 4 + nt)) * 2;
    WB[cb * 512 + r2]       = hi;         // plane 0
    WB[(cb + 1) * 512 + r2] = f2bf(lo);   // plane 1
    return;
  } i -= 73728;
  if (i < 128){ ws[O_B2 + i] = ldin(c2b, i, F); return; } i -= 128;
  if (i < 32768){ ws[O_FCW + i] = ldin(fcw, i, F); return; } i -= 32768;
  if (i < 256){ ws[O_FCB + i] = ldin(fcb, i, F); return; } i -= 256;
  if (i < 65536){  // WDW transposed: dst[k*256+df] = src[df*256+k]
    int k = i >> 8, df = i & 255;
    ws[O_WDW + i] = ldin(wdw, (size_t)df * 256 + k, F); return;
  } i -= 65536;
  if (i < 256){ ws[O_WDB + i] = ldin(wdb, i, F); return; } i -= 256;
  if (i < 4096){   // B_w transposed: dst[k*16+s] = src[s*256+k]
    int k = i >> 4, s = i & 15;
    ws[O_BWO + i] = ldin(bw, (size_t)s * 256 + k, F); return;
  } i -= 4096;
  if (i < 16){ ws[O_BBO + i] = ldin(bb, i, F); return; } i -= 16;
  if (i < 4096){   // C_w transposed
    int k = i >> 4, s = i & 15;
    ws[O_CWO + i] = ldin(cw, (size_t)s * 256 + k, F); return;
  } i -= 4096;
  if (i < 16){ ws[O_CBO + i] = ldin(cb, i, F); return; } i -= 16;
  if (i < 65536){  // out_w transposed: dst[k*256+df] = src[df*256+k]
    int k = i >> 8, df = i & 255;
    ws[O_OW + i] = ldin(ow, (size_t)df * 256 + k, F); return;
  } i -= 65536;
  if (i < 256){ ws[O_OB + i] = ldin(ob, i, F); return; } i -= 256;
  if (i < 4096){ ws[O_AF + i] = -expf(ldin(alog, i, F)); return; } i -= 4096;
  if (i < 256){ ws[O_DD + i] = ldin(dvec, i, F); return; } i -= 256;
  if (i < 256){ ws[O_LNG + i] = ldin(lng, i, F); return; } i -= 256;
  if (i < 256){ ws[O_LNB + i] = ldin(lnb, i, F); }
}

// ---------------- K1: per-patch conv1 + MFMA conv2 (bf16 3-split, N-passed) ----------
// R6: kill R5's residual spill (450 MB scratch: 64 AGPR acc ate half the 128-reg
// budget). Retile: 8 waves x 1 M-tile; N split into 2 passes of 2 N-tiles ->
// acc = 32 regs, frags = 24, total ~90 < 128 -> no spill at 2 blocks/CU.
// Both ic-chunks' A planes live in LDS (41.5 KB); conv1 runs once (pin computed
// once). Per-acc-element MFMA order identical to R5 (hh, lh, hl; chunk0 then
// chunk1) -> bitwise-identical C elements; only pool partial grouping changes.
__global__ __launch_bounds__(512, 4) void k_patch(const void* __restrict__ img,
                                                  const float* __restrict__ ws,
                                                  float* __restrict__ feats)
{
  __shared__ __align__(16) ushortb Abuf[4 * 10368]; // [c][plane hi/lo][18*18*32]
  __shared__ float timg[768];      // 3KB input tile [3 c][256 px]
  __shared__ float pool8[8 * 128]; // per-wave (per-M-tile) pooled partials
  __shared__ float pm[128];        // pooled mean
  const int F = ((const int*)(ws + O_FLAG))[0];
  const float* W1 = ws + O_W1;  const float* B1 = ws + O_B1;
  const float* FCW = ws + O_FCW; const float* FCB = ws + O_FCB;
  const s16x8* BF = (const s16x8*)(ws + O_W2);   // fragment-major B

  int blk = blockIdx.x; int b = blk >> 10; int pidx = blk & 1023;
  int ph = pidx >> 5, pw = pidx & 31;
  int tid = threadIdx.x;

  // stage input tile (16x16x3) into LDS
  if (tid < 256){
    int y = tid >> 4, x = tid & 15;
    #pragma unroll
    for (int c = 0; c < 3; c++)
      timg[c * 256 + tid] =
        ldin(img, (((size_t)b * 3 + c) * 512 + (ph * 16 + y)) * 512 + (pw * 16 + x), F);
  }
  // zero A boundary rows (conv1 writes interior only, zeros persist)
  {
    uint4 z4 = make_uint4(0u, 0u, 0u, 0u);
    for (int r = tid; r < 324; r += 512){
      int y = r / 18, x = r - y * 18;
      if (y == 0 || y == 17 || x == 0 || x == 17){
        #pragma unroll
        for (int pl = 0; pl < 4; pl++)
          #pragma unroll
          for (int m = 0; m < 4; m++)
            *(uint4*)&Abuf[pl * 10368 + r * 32 + m * 8] = z4;
      }
    }
  }
  __syncthreads();

  int wv = tid >> 6, ln = tid & 63;
  int l31 = ln & 31, lhi = ln >> 5;
  int xcol = ln & 15, yrow = l31 >> 4;
  int p = tid & 255, og = tid >> 8;
  int ii = p >> 4, jj = p & 15;

  // conv1 (both chunks, pin computed once): thread = (pixel p, half og of 16 oc/chunk)
  {
    float pin[27];
    #pragma unroll
    for (int cc = 0; cc < 3; cc++)
      #pragma unroll
      for (int dy = 0; dy < 3; dy++)
        #pragma unroll
        for (int dx = 0; dx < 3; dx++){
          int y = ii + dy - 1, x = jj + dx - 1;
          bool ok = (y >= 0 && y < 16 && x >= 0 && x < 16);
          pin[cc * 9 + dy * 3 + dx] = ok ? timg[cc * 256 + y * 16 + x] : 0.f;
        }
    int r = (ii + 1) * 18 + (jj + 1);
    int swz = ((r >> 1) & 3) << 3;
    for (int c = 0; c < 2; c++){
      int oc0 = c * 32 + og * 16;
      int w1base = __builtin_amdgcn_readfirstlane(oc0 * 27);
      const float* W1g = W1 + w1base;
      #pragma unroll
      for (int g = 0; g < 2; g++){
        float av[8];
        #pragma unroll
        for (int o = 0; o < 8; o++){
          float a = B1[oc0 + g * 8 + o];
          #pragma unroll
          for (int t = 0; t < 27; t++) a += W1g[(g * 8 + o) * 27 + t] * pin[t];
          av[o] = gelu_f(a);
        }
        unsigned int hp[4], lp[4];
        #pragma unroll
        for (int q = 0; q < 4; q++){
          float v0 = av[2 * q], v1 = av[2 * q + 1];
          ushortb h0 = f2bf(v0), h1 = f2bf(v1);
          float l0 = v0 - bf2f(h0), l1 = v1 - bf2f(h1);
          hp[q] = (unsigned int)h0 | ((unsigned int)h1 << 16);
          lp[q] = (unsigned int)f2bf(l0) | ((unsigned int)f2bf(l1) << 16);
        }
        int idx = r * 32 + (((og * 2 + g) << 3) ^ swz);
        *(uint4*)&Abuf[c * 20736 + idx] = make_uint4(hp[0], hp[1], hp[2], hp[3]);
        *(uint4*)&Abuf[c * 20736 + 10368 + idx] = make_uint4(lp[0], lp[1], lp[2], lp[3]);
      }
    }
  }
  __syncthreads();

  // conv2 via 32x32x16 MFMA: wave wv owns M-tile wv (px rows 2wv, 2wv+1).
  // 2 N-passes of 2 N-tiles; K = 2 chunks x 18 steps; 3-split per step.
  #pragma unroll
  for (int pass = 0; pass < 2; pass++){
    fx16 acc0, acc1;
    #pragma unroll
    for (int r = 0; r < 16; r++){ acc0[r] = 0.f; acc1[r] = 0.f; }

    for (int c = 0; c < 2; c++){
      const ushortb* Ah = Abuf + c * 20736;
      const s16x8* bfp = BF + (size_t)((c * 144 + pass * 4) * 64 + ln);
      for (int s = 0; s < 18; s++){
        int tap = s >> 1, ksub = s & 1;
        int dyq = tap / 3, dxq = tap - dyq * 3;
        int icq0 = (ksub << 1) + lhi;                 // 8-ic slot 0..3
        int rA = (wv * 2 + yrow + dyq) * 18 + (xcol + dxq);
        int iA = rA * 32 + ((icq0 ^ ((rA >> 1) & 3)) << 3);
        s16x8 fa_h = *(const s16x8*)&Ah[iA];
        s16x8 fa_l = *(const s16x8*)&Ah[10368 + iA];
        const s16x8* bq = bfp + (s << 9);
        s16x8 fb0h = bq[0];
        s16x8 fb0l = bq[64];
        s16x8 fb1h = bq[128];
        s16x8 fb1l = bq[192];
        acc0 = __builtin_amdgcn_mfma_f32_32x32x16_bf16(fa_h, fb0h, acc0, 0, 0, 0);
        acc1 = __builtin_amdgcn_mfma_f32_32x32x16_bf16(fa_h, fb1h, acc1, 0, 0, 0);
        acc0 = __builtin_amdgcn_mfma_f32_32x32x16_bf16(fa_l, fb0h, acc0, 0, 0, 0);
        acc1 = __builtin_amdgcn_mfma_f32_32x32x16_bf16(fa_l, fb1h, acc1, 0, 0, 0);
        acc0 = __builtin_amdgcn_mfma_f32_32x32x16_bf16(fa_h, fb0l, acc0, 0, 0, 0);
        acc1 = __builtin_amdgcn_mfma_f32_32x32x16_bf16(fa_h, fb1l, acc1, 0, 0, 0);
      }
    }

    // pool this pass's 2 N-tiles: C/D col oc = nt*32 + l31, rows = 16 regs x lhi.
    #pragma unroll
    for (int n = 0; n < 2; n++){
      int nt = pass * 2 + n;
      float bz = ws[O_B2 + nt * 32 + l31];
      float sum = 0.f;
      #pragma unroll
      for (int r = 0; r < 16; r++)
        sum += gelu_f(((n == 0) ? acc0[r] : acc1[r]) + bz);
      sum += __shfl_xor(sum, 32);
      if (lhi == 0) pool8[wv * 128 + nt * 32 + l31] = sum;
    }
  }
  __syncthreads();
  if (tid < 128){
    float sv = 0.f;
    #pragma unroll
    for (int w = 0; w < 8; w++) sv += pool8[w * 128 + tid];
    pm[tid] = sv * (1.f / 256.f);
  }
  __syncthreads();

  // fc 128 -> 256 (threads 0..255)
  if (tid < 256){
    int df = tid;
    float s = FCB[df];
    const float* wrow = FCW + (size_t)df * 128;
    #pragma unroll
    for (int k = 0; k < 128; k += 4)
      s += wrow[k] * pm[k] + wrow[k + 1] * pm[k + 1]
         + wrow[k + 2] * pm[k + 2] + wrow[k + 3] * pm[k + 3];
    feats[((size_t)(b * 1024 + pidx)) * 256 + df] = s;
  }
}

// ---------------- K3: structure (rsem fused + Boruvka MST + adjacency + level BFS) ---
__device__ __forceinline__ void edge_uv(int e, int& u, int& v){
  if (e < 1953){
    int i = e / 63; int k = e - i * 63;
    if (k < 62){ int j = k >> 1; u = i * 32 + j; v = (k & 1) ? u + 32 : u + 1; }
    else { u = i * 32 + 31; v = u + 32; }
  } else { u = 31 * 32 + (e - 1953); v = u + 1; }
}

__global__ __launch_bounds__(1024) void k_struct(float* __restrict__ ws)
{
  __shared__ float s_ninv[1024];
  __shared__ float s_w[NEDGE];
  __shared__ float s_r[1024];
  __shared__ int   s_comp[1024];
  __shared__ int   s_link[1024];
  __shared__ int   s_link2[1024];
  __shared__ unsigned long long s_best[1024];
  __shared__ unsigned char  s_mst[NEDGE];
  __shared__ unsigned short s_adj[1024 * 4];
  __shared__ unsigned char  s_deg[1024];
  __shared__ unsigned short s_bfs[1024];
  __shared__ short          s_parof[1024];
  __shared__ unsigned short s_o2b[1024];
  __shared__ unsigned short s_cur[1024];
  __shared__ unsigned short s_nxt[1024];
  __shared__ unsigned short s_off[1025];
  __shared__ unsigned short s_loff2[1026];
  __shared__ unsigned long long s_rootkey;
  __shared__ int s_ncomp, s_cursz, s_bfscnt, s_nextsz, s_nlvl;

  int b = blockIdx.x; int tid = threadIdx.x;
  const float* feats = ws + O_FEATS + (size_t)b * NP * DFEAT;

  // norms + fused r_sem + defensive init
  {
    const float4* f4 = (const float4*)(feats + (size_t)tid * 256);
    const float4* g4 = (const float4*)(ws + O_GPROJ + b * 256);
    float d = 0.f, gdot = 0.f;
    for (int k = 0; k < 64; k++){
      float4 q = f4[k]; float4 g = g4[k];
      d += q.x*q.x + q.y*q.y + q.z*q.z + q.w*q.w;
      gdot += q.x*g.x + q.y*g.y + q.z*g.z + q.w*g.w;
    }
    s_ninv[tid] = 1.f / fmaxf(sqrtf(d), 1e-12f);
    float r = 1.f / (1.f + expf(-gdot * (1.f / 16.f)));
    s_r[tid] = r;
    ws[O_RSEM + b * NP + tid] = r;      // k_xdelta consumes this
    s_comp[tid] = tid;
    s_deg[tid] = 0;
    s_bfs[tid] = (unsigned short)tid;
    s_o2b[tid] = (unsigned short)tid;
    s_parof[tid] = -1;
  }
  for (int e = tid; e < NEDGE; e += 1024) s_mst[e] = 0;
  __syncthreads();

  // edge weights
  for (int e = tid; e < NEDGE; e += 1024){
    int u, v; edge_uv(e, u, v);
    const float4* fu = (const float4*)(feats + (size_t)u * 256);
    const float4* fv = (const float4*)(feats + (size_t)v * 256);
    float d = 0.f;
    for (int k = 0; k < 64; k++){ float4 a = fu[k], c = fv[k]; d += a.x*c.x + a.y*c.y + a.z*c.z + a.w*c.w; }
    float cosv = d * s_ninv[u] * s_ninv[v];
    s_w[e] = (1.f - s_r[u]) * (1.f - s_r[v]) * (-cosv) + 1e-6f;
  }
  __syncthreads();

  // Boruvka rounds (root chase instead of fixed pointer-jumping: exact, fewer barriers)
  for (int round = 0; round < 12; round++){
    s_best[tid] = ~0ull;
    __syncthreads();
    for (int e = tid; e < NEDGE; e += 1024){
      int u, v; edge_uv(e, u, v);
      int cu = s_comp[u], cv = s_comp[v];
      if (cu != cv){
        unsigned long long key = (((unsigned long long)f2sort(s_w[e])) << 32) | (unsigned int)e;
        atomicMin(&s_best[cu], key);
        atomicMin(&s_best[cv], key);
      }
    }
    __syncthreads();
    int l = tid;
    if (s_comp[tid] == tid && s_best[tid] != ~0ull){
      int e = (int)(s_best[tid] & 0xffffffffu);
      int u, v; edge_uv(e, u, v);
      s_mst[e] = 1;
      int cu = s_comp[u], cv = s_comp[v];
      l = (cu == tid) ? cv : cu;
    }
    s_link[tid] = l;
    __syncthreads();
    if (l != tid && s_link[l] == tid && tid < l) s_link[tid] = tid; // break 2-cycles
    __syncthreads();
    // chase to root (links static: only 2-cycles existed, now broken -> acyclic)
    {
      int x = tid;
      int p = s_link[x];
      while (p != x){ x = p; p = s_link[x]; }
      s_link2[tid] = x;
    }
    __syncthreads();
    s_comp[tid] = s_link2[s_comp[tid]];
    if (tid == 0) s_ncomp = 0;
    __syncthreads();
    if (s_comp[tid] == tid) atomicAdd(&s_ncomp, 1);
    __syncthreads();
    if (s_ncomp == 1) break;
    __syncthreads();
  }
  __syncthreads();

  // weight-ordered adjacency (== Kruskal insertion order for unique MST)
  {
    int v = tid; int i = v >> 5, j = v & 31;
    float wloc[4]; int nloc[4]; int d = 0;
    if (j > 0){ int e = (i < 31) ? (i * 63 + 2 * (j - 1)) : (1953 + (j - 1));
      if (s_mst[e]){ wloc[d] = s_w[e]; nloc[d] = v - 1; d++; } }
    if (j < 31){ int e = (i < 31) ? (i * 63 + 2 * j) : (1953 + j);
      if (s_mst[e]){ wloc[d] = s_w[e]; nloc[d] = v + 1; d++; } }
    if (i > 0){ int e = (i - 1) * 63 + ((j < 31) ? (2 * j + 1) : 62);
      if (s_mst[e]){ wloc[d] = s_w[e]; nloc[d] = v - 32; d++; } }
    if (i < 31){ int e = i * 63 + ((j < 31) ? (2 * j + 1) : 62);
      if (s_mst[e]){ wloc[d] = s_w[e]; nloc[d] = v + 32; d++; } }
    for (int a = 1; a < d; a++){
      float wv = wloc[a]; int nv = nloc[a]; int c = a - 1;
      while (c >= 0 && wloc[c] > wv){ wloc[c+1] = wloc[c]; nloc[c+1] = nloc[c]; c--; }
      wloc[c+1] = wv; nloc[c+1] = nv;
    }
    s_deg[v] = (unsigned char)d;
    for (int a = 0; a < d; a++) s_adj[v * 4 + a] = (unsigned short)nloc[a];
  }
  // root = argmax r (first index on ties)
  if (tid == 0) s_rootkey = 0ull;
  __syncthreads();
  {
    unsigned long long key = (((unsigned long long)f2sort(s_r[tid])) << 32) | (unsigned int)(1023 - tid);
    atomicMax(&s_rootkey, key);
  }
  __syncthreads();
  int root = 1023 - (int)(s_rootkey & 0xffffffffu);

  // level-parallel tree BFS (records level offsets for k_scan)
  if (tid == 0){
    s_bfs[0] = (unsigned short)root; s_o2b[root] = 0; s_parof[root] = -1;
    s_cur[0] = (unsigned short)root; s_cursz = 1; s_bfscnt = 1; s_nlvl = 0;
  }
  __syncthreads();
  for (int lev = 0; lev < 1024; lev++){
    int csz = s_cursz;
    if (csz <= 0) break;
    // wave-parallel exclusive scan of child counts
    if (tid < 64){
      int runbase = 0;
      for (int t0 = 0; t0 < csz; t0 += 64){
        int t = t0 + tid;
        int cnt = 0;
        if (t < csz){
          int n = s_cur[t];
          cnt = (int)s_deg[n] - (s_parof[n] >= 0 ? 1 : 0);
        }
        int v = cnt;
        #pragma unroll
        for (int off = 1; off < 64; off <<= 1){
          int u2 = __shfl_up(v, off);
          if (tid >= off) v += u2;
        }
        if (t < csz) s_off[t] = (unsigned short)(runbase + v - cnt);
        runbase += __shfl(v, 63);
      }
      if (tid == 0){
        if (s_nlvl < 1025){ s_loff2[s_nlvl] = (unsigned short)(s_bfscnt - csz); }
        s_nlvl++;
        s_nextsz = runbase;
      }
    }
    __syncthreads();
    if (tid < csz){
      int n = s_cur[tid]; int base = s_off[tid]; int k = 0;
      int pn = s_parof[n]; int dg = s_deg[n];
      for (int a = 0; a < dg; a++){
        int c = s_adj[n * 4 + a];
        if (c == pn) continue;
        s_parof[c] = (short)n;
        if (base + k < 1024) s_nxt[base + k] = (unsigned short)c;
        int pos = s_bfscnt + base + k;
        if (pos < 1024){
          s_bfs[pos] = (unsigned short)c;
          s_o2b[c] = (unsigned short)pos;
        }
        k++;
      }
    }
    __syncthreads();
    if (tid == 0){ s_bfscnt += s_nextsz; s_cursz = (s_nextsz > 1024) ? 1024 : s_nextsz; }
    __syncthreads();
    if (tid < s_cursz) s_cur[tid] = s_nxt[tid];
    __syncthreads();
  }
  __syncthreads();

  int* BFSo = (int*)(ws + O_BFS);
  int* PARo = (int*)(ws + O_PAR);
  {
    int node = s_bfs[tid] & 1023;
    BFSo[b * 1024 + tid] = node;
    int p = s_parof[node];
    PARo[b * 1024 + tid] = (p < 0) ? -1 : (int)(s_o2b[p] & 1023);
  }
  // export level table: [nlvl, loff[0..nlvl]] (loff[nlvl] = NP)
  {
    int* LVLo = (int*)(ws + O_LVL) + b * 1040;
    int nl = s_nlvl; if (nl > 1024) nl = 1024;
    if (tid == 0){ LVLo[0] = nl; LVLo[1 + nl] = NP; }
    if (tid < nl) LVLo[1 + tid] = (int)s_loff2[tid];
  }
}

// ---------------- K4: X, delta, Bp, Cp (k-major coalesced weight reads) --------------
__global__ __launch_bounds__(256) void k_xdelta(float* __restrict__ ws)
{
  __shared__ float xs[256];
  int blk = blockIdx.x; int b = blk >> 10, i = blk & 1023; int df = threadIdx.x;
  const int* BFSo = (const int*)(ws + O_BFS);
  int node = BFSo[b * 1024 + i] & 1023;
  float rs = ws[O_RSEM + b * 1024 + node];
  float xv = ws[O_FEATS + ((size_t)(b * 1024 + node)) * 256 + df] + rs * ws[O_GPRIM + b * 256 + df];
  xs[df] = xv;
  ws[O_X + ((size_t)(b * 1024 + i)) * 256 + df] = xv;
  __syncthreads();
  {
    const float* WT = ws + O_WDW;
    float z = ws[O_WDB + df];
    #pragma unroll 8
    for (int k = 0; k < 256; k++)
      z += WT[(size_t)k * 256 + df] * xs[k];
    float sp = fmaxf(z, 0.f) + log1pf(expf(-fabsf(z)));
    ws[O_DELTA + ((size_t)(b * 1024 + i)) * 256 + df] = sp * (1.f + 2.f * rs);
  }
  if (df < 32){
    int s = df & 15;
    const float* WT = ws + ((df < 16) ? O_BWO : O_CWO);   // [k][s]
    float a = ws[((df < 16) ? O_BBO : O_CBO) + s];
    #pragma unroll 8
    for (int k = 0; k < 256; k++) a += WT[k * 16 + s] * xs[k];
    ws[((df < 16) ? O_BP : O_CP) + (size_t)(b * 1024 + i) * 16 + s] = a;
  }
}

// ---------------- K5: tree scan, LEVEL-PARALLEL, 256 threads -------------------------
__global__ __launch_bounds__(256) void k_scan(float* __restrict__ ws)
{
  __shared__ float h[NP * DSTATE];   // 64 KB: h[pos][s]
  __shared__ float xs[NP];
  __shared__ float ds[NP];
  __shared__ int   par_s[NP];
  __shared__ int   bfs_s[NP];
  int blk = blockIdx.x; int b = blk >> 8, f = blk & 255;
  int tid = threadIdx.x;
  int g = tid >> 4, s = tid & 15;
  const int* PARo = (const int*)(ws + O_PAR);
  const int* BFSo = (const int*)(ws + O_BFS);
  const int* LVLo = (const int*)(ws + O_LVL) + b * 1040;
  for (int i = tid; i < NP; i += 256){
    xs[i] = ws[O_X     + ((size_t)(b * NP + i)) * DFEAT + f];
    ds[i] = ws[O_DELTA + ((size_t)(b * NP + i)) * DFEAT + f];
    par_s[i] = PARo[b * NP + i];
    bfs_s[i] = BFSo[b * NP + i] & 1023;
  }
  __syncthreads();

  int nlvl = LVLo[0];
  bool degen = (nlvl < 1 || nlvl > NP);
  if (degen) nlvl = NP;               // fallback: one node per level == serial order

  float Aln = ws[O_AF + f * 16 + s];
  float Dv  = ws[O_DD + f];
  const float* Bp = ws + O_BP + (size_t)b * NP * DSTATE;
  const float* Cp = ws + O_CP + (size_t)b * NP * DSTATE;
  float* Yr = ws + O_YR + (size_t)b * NP * DFEAT;

  for (int l = 0; l < nlvl; l++){
    int o0, o1;
    if (degen){ o0 = l; o1 = l + 1; }
    else {
      o0 = LVLo[1 + l]; o1 = LVLo[2 + l];
      o0 = (o0 < 0) ? 0 : ((o0 > NP) ? NP : o0);
      o1 = (o1 < o0) ? o0 : ((o1 > NP) ? NP : o1);
    }
    for (int i = o0 + g; i < o1; i += 16){
      int p = par_s[i];
      float d = ds[i], x = xs[i];
      float hp = (p >= 0 && p < i) ? h[p * 16 + s] : 0.f;
      float hn = expf(d * Aln) * hp + d * Bp[i * 16 + s] * x;
      h[i * 16 + s] = hn;
      float t = hn * Cp[i * 16 + s];
      t += __shfl_xor(t, 1); t += __shfl_xor(t, 2);
      t += __shfl_xor(t, 4); t += __shfl_xor(t, 8);
      if (s == 0) Yr[(size_t)bfs_s[i] * DFEAT + f] = t + Dv * x;
    }
    __syncthreads();   // orders level l writes vs l+1 reads
  }
}

// ---------------- K6: out GEMM (k-major coalesced) + LayerNorm -> out dtype ----------
__global__ __launch_bounds__(256) void k_outln(const float* __restrict__ ws,
                                               void* __restrict__ out)
{
  __shared__ float yl[256];
  __shared__ float red[8];
  const int F = ((const int*)(ws + O_FLAG))[0];
  int blk = blockIdx.x; int b = blk >> 10, p = blk & 1023; int df = threadIdx.x;
  yl[df] = ws[O_YR + ((size_t)(b * 1024 + p)) * 256 + df];
  __syncthreads();
  const float* OT = ws + O_OW;   // [k][df]
  float a = ws[O_OB + df];
  #pragma unroll 8
  for (int k = 0; k < 256; k++)
    a += OT[(size_t)k * 256 + df] * yl[k];
  int lane = df & 63, wid = df >> 6;
  float t = a;
  t += __shfl_xor(t, 1); t += __shfl_xor(t, 2);  t += __shfl_xor(t, 4);
  t += __shfl_xor(t, 8); t += __shfl_xor(t, 16); t += __shfl_xor(t, 32);
  if (lane == 0) red[wid] = t;
  __syncthreads();
  float mu = (red[0] + red[1] + red[2] + red[3]) * (1.f / 256.f);
  float dv = a - mu;
  float t2 = dv * dv;
  t2 += __shfl_xor(t2, 1); t2 += __shfl_xor(t2, 2);  t2 += __shfl_xor(t2, 4);
  t2 += __shfl_xor(t2, 8); t2 += __shfl_xor(t2, 16); t2 += __shfl_xor(t2, 32);
  if (lane == 0) red[4 + wid] = t2;
  __syncthreads();
  float var = (red[4] + red[5] + red[6] + red[7]) * (1.f / 256.f);
  float o = ws[O_LNG + df] * dv / sqrtf(var + 1e-5f) + ws[O_LNB + df];
  size_t idx = ((size_t)(b * 1024 + p)) * 256 + df;
  if (F) ((ushortb*)out)[idx] = f2bf(o);
  else   ((float*)out)[idx]   = o;
}

// ---------------- launch ----------------
extern "C" void kernel_launch(void* const* d_in, const int* in_sizes, int n_in,
                              void* d_out, int out_size, void* d_ws, size_t ws_size,
                              hipStream_t stream)
{
  (void)in_sizes; (void)n_in; (void)out_size; (void)ws_size;
  const void* img   = d_in[0];
  const void* lang  = d_in[1];
  const void* c1w   = d_in[2];
  const void* c1b   = d_in[3];
  const void* c2w   = d_in[4];
  const void* c2b   = d_in[5];
  const void* fcw   = d_in[6];
  const void* fcb   = d_in[7];
  const void* wgate = d_in[8];
  const void* wgp   = d_in[9];
  const void* alog  = d_in[10];
  const void* dvec  = d_in[11];
  const void* bw    = d_in[12];
  const void* bb    = d_in[13];
  const void* cw    = d_in[14];
  const void* cb    = d_in[15];
  const void* wdw   = d_in[16];
  const void* wdb   = d_in[17];
  const void* ow    = d_in[18];
  const void* ob    = d_in[19];
  const void* lng   = d_in[20];
  const void* lnb   = d_in[21];
  float* ws = (float*)d_ws;

  k_sniff<<<1, 256, 0, stream>>>(img, ws);
  k_convert<<<990 + 2048 + 256, 256, 0, stream>>>(c1w, c1b, c2w, c2b, fcw, fcb, alog, dvec,
                                                  bw, bb, cw, cb, wdw, wdb, ow, ob, lng, lnb,
                                                  lang, wgate, wgp, ws);
  k_patch<<<2048, 512, 0, stream>>>(img, ws, ws + O_FEATS);
  k_struct<<<2, 1024, 0, stream>>>(ws);
  k_xdelta<<<2048, 256, 0, stream>>>(ws);
  k_scan<<<NB * DFEAT, 256, 0, stream>>>(ws);
  k_outln<<<2048, 256, 0, stream>>>(ws, d_out);
}

// Round 7
// 850.826 us; speedup vs baseline: 1.5457x; 1.0209x over previous
//
#include <hip/hip_runtime.h>
#include <cstddef>
#include <cstdint>

// ---------------- constants ----------------
#define NB    2
#define NP    1024    // patches per image
#define DFEAT 256
#define DSTATE 16
#define NEDGE 1984    // grid edges: 31*63 + 31

typedef unsigned short ushortb;

// MFMA fragment types (gfx950 32x32x16 bf16)
typedef float fx16 __attribute__((ext_vector_type(16)));
typedef short s16x8 __attribute__((ext_vector_type(8)));

// ---------------- helpers ----------------
__device__ __forceinline__ float bf2f(unsigned short u){
  union { unsigned int i; float f; } c; c.i = ((unsigned int)u) << 16; return c.f;
}
__device__ __forceinline__ unsigned short f2bf(float f){
  union { float f; unsigned int i; } c; c.f = f;
  unsigned int u = c.i;
  unsigned int r = (u + 0x7fffu + ((u >> 16) & 1u)) >> 16;
  return (unsigned short)r;
}
// dtype-generic input load: isbf ? bf16[i] : fp32[i]
__device__ __forceinline__ float ldin(const void* p, size_t i, int isbf){
  return isbf ? bf2f(((const ushortb*)p)[i]) : ((const float*)p)[i];
}
__device__ __forceinline__ float gelu_f(float x){
  return 0.5f * x * (1.0f + erff(x * 0.70710678118654752f));
}
__device__ __forceinline__ unsigned int f2sort(float f){
  union { float f; unsigned int i; } c; c.f = f;
  return (c.i & 0x80000000u) ? ~c.i : (c.i | 0x80000000u);
}

// ---------------- ws layout (float element offsets) ----------------
constexpr size_t AL(size_t x){ return (x + 63) & ~(size_t)63; }
constexpr size_t O_W1    = 0;                       // 1728  conv1 w fp32
constexpr size_t O_B1    = AL(O_W1 + 1728);         // 64
constexpr size_t O_W2    = AL(O_B1 + 64);           // 73728 floats = 147456 bf16, FRAGMENT-MAJOR
                                                    //   chunked for K-split: sg = c*18 + tap*2 + ksub
constexpr size_t O_B2    = AL(O_W2 + 73728);        // 128
constexpr size_t O_FCW   = AL(O_B2 + 128);          // 32768 [df][128]
constexpr size_t O_FCB   = AL(O_FCW + 32768);       // 256
constexpr size_t O_WDW   = AL(O_FCB + 256);         // 65536 TRANSPOSED [k][df]
constexpr size_t O_WDB   = AL(O_WDW + 65536);       // 256
constexpr size_t O_BWO   = AL(O_WDB + 256);         // 4096 TRANSPOSED [k][s]
constexpr size_t O_BBO   = AL(O_BWO + 4096);        // 16
constexpr size_t O_CWO   = AL(O_BBO + 16);          // 4096 TRANSPOSED [k][s]
constexpr size_t O_CBO   = AL(O_CWO + 4096);        // 16
constexpr size_t O_OW    = AL(O_CBO + 16);          // 65536 TRANSPOSED [k][df]
constexpr size_t O_OB    = AL(O_OW + 65536);        // 256
constexpr size_t O_AF    = AL(O_OB + 256);          // 4096  A = -exp(A_log), [f][s]
constexpr size_t O_DD    = AL(O_AF + 4096);         // 256
constexpr size_t O_LNG   = AL(O_DD + 256);          // 256
constexpr size_t O_LNB   = AL(O_LNG + 256);         // 256
constexpr size_t O_FEATS = AL(O_LNB + 256);         // 2*1024*256
constexpr size_t O_GPROJ = AL(O_FEATS + (size_t)NB*NP*DFEAT); // 512
constexpr size_t O_GPRIM = AL(O_GPROJ + NB*DFEAT);  // 512
constexpr size_t O_RSEM  = AL(O_GPRIM + NB*DFEAT);  // 2048
constexpr size_t O_BFS   = AL(O_RSEM + NB*NP);      // 2048 (int)
constexpr size_t O_PAR   = AL(O_BFS + NB*NP);       // 2048 (int)
constexpr size_t O_X     = AL(O_PAR + NB*NP);       // 2*1024*256
constexpr size_t O_DELTA = AL(O_X + (size_t)NB*NP*DFEAT);
constexpr size_t O_BP    = AL(O_DELTA + (size_t)NB*NP*DFEAT); // 2*1024*16
constexpr size_t O_CP    = AL(O_BP + NB*NP*DSTATE);
constexpr size_t O_YR    = AL(O_CP + NB*NP*DSTATE); // 2*1024*256
constexpr size_t O_FLAG  = AL(O_YR + (size_t)NB*NP*DFEAT);    // 1 int: is-bf16 flag
constexpr size_t O_LVL   = AL(O_FLAG + 64);         // NB*1040 ints: [nlvl, loff[0..nlvl]]

// ---------------- K-1: sniff input dtype (bf16 vs fp32) from images buffer -----------
__global__ __launch_bounds__(256) void k_sniff(const void* img, float* ws)
{
  __shared__ int cnt;
  int tid = threadIdx.x;
  if (tid == 0) cnt = 0;
  __syncthreads();
  const ushortb* u = (const ushortb*)img;
  int local = 0;
  for (int k = 0; k < 16; k++){
    unsigned short v = u[tid * 16 + k];
    if (v == 0 || v == 0x8000u){ local++; continue; }
    float f = fabsf(bf2f(v));
    if (f >= 1e-8f && f <= 64.f) local++;    // plausible N(0,1) bf16
  }
  atomicAdd(&cnt, local);
  __syncthreads();
  if (tid == 0) ((int*)(ws + O_FLAG))[0] = (cnt >= 3900) ? 1 : 0;  // >=95% plausible
}

// ---------------- K0: convert weights + zero YR + g_proj/g_prime (all fused) ---------
// blocks [0,990): weight convert; [990,3038): YR zero; [3038,3294): gmm rows.
__global__ __launch_bounds__(256) void k_convert(const void* c1w, const void* c1b, const void* c2w,
                          const void* c2b, const void* fcw, const void* fcb,
                          const void* alog, const void* dvec,
                          const void* bw, const void* bb, const void* cw, const void* cb,
                          const void* wdw, const void* wdb,
                          const void* ow, const void* ob,
                          const void* lng, const void* lnb,
                          const void* lang, const void* wgate, const void* wgp,
                          float* ws)
{
  const int F = ((const int*)(ws + O_FLAG))[0];
  if (blockIdx.x >= 3038){  // gmm branch: wave-per-row coalesced dual GEMV
    int row = (blockIdx.x - 3038) * 4 + (threadIdx.x >> 6);
    int lane = threadIdx.x & 63;
    int mat = row >> 9;
    int b   = (row >> 8) & 1;
    int df  = row & 255;
    const void* W = mat ? wgp : wgate;
    float s = 0.f;
    for (int k = lane; k < 896; k += 64)
      s += ldin(lang, (size_t)b * 896 + k, F) * ldin(W, (size_t)df * 896 + k, F);
    s += __shfl_xor(s, 1);  s += __shfl_xor(s, 2);  s += __shfl_xor(s, 4);
    s += __shfl_xor(s, 8);  s += __shfl_xor(s, 16); s += __shfl_xor(s, 32);
    if (lane == 0) ws[(mat ? O_GPRIM : O_GPROJ) + b * 256 + df] = s;
    return;
  }
  if (blockIdx.x >= 990){   // init branch: zero YR
    size_t i2 = (size_t)(blockIdx.x - 990) * 256 + threadIdx.x;
    if (i2 < (size_t)NB * NP * DFEAT) ws[O_YR + i2] = 0.f;
    return;
  }
  int i = blockIdx.x * 256 + threadIdx.x;
  if (i < 1728){ ws[O_W1 + i] = ldin(c1w, i, F); return; } i -= 1728;
  if (i < 64){ ws[O_B1 + i] = ldin(c1b, i, F); return; } i -= 64;
  if (i < 73728){
    // fragment-major bf16-split conv2 weights for chunked 32x32x16 MFMA.
    // step sg = c*18 + tap*2 + ksub (c = ic chunk of 32).
    // lane ln holds oc = nt*32 + (ln&31), k-in-step = (ln>>5)*8 + e.
    int sg = i >> 11;           // 0..35
    int r = i & 2047;
    int nt = r >> 9;
    int r2 = r & 511;           // ln*8 + e
    int ln = r2 >> 3, e = r2 & 7;
    int c  = sg / 18, s = sg - c * 18;
    int tap = s >> 1, ksub = s & 1;
    int oc = nt * 32 + (ln & 31);
    int ic = c * 32 + ksub * 16 + (ln >> 5) * 8 + e;
    float v = ldin(c2w, (size_t)(oc * 64 + ic) * 9 + tap, F);
    ushortb hi = f2bf(v);
    float lo = v - bf2f(hi);
    ushortb* WB = (ushortb*)(ws + O_W2);
    size_t cb = ((size_t)(sg * 4 + nt)) * 2;
    WB[cb * 512 + r2]       = hi;         // plane 0
    WB[(cb + 1) * 512 + r2] = f2bf(lo);   // plane 1
    return;
  } i -= 73728;
  if (i < 128){ ws[O_B2 + i] = ldin(c2b, i, F); return; } i -= 128;
  if (i < 32768){ ws[O_FCW + i] = ldin(fcw, i, F); return; } i -= 32768;
  if (i < 256){ ws[O_FCB + i] = ldin(fcb, i, F); return; } i -= 256;
  if (i < 65536){  // WDW transposed: dst[k*256+df] = src[df*256+k]
    int k = i >> 8, df = i & 255;
    ws[O_WDW + i] = ldin(wdw, (size_t)df * 256 + k, F); return;
  } i -= 65536;
  if (i < 256){ ws[O_WDB + i] = ldin(wdb, i, F); return; } i -= 256;
  if (i < 4096){   // B_w transposed: dst[k*16+s] = src[s*256+k]
    int k = i >> 4, s = i & 15;
    ws[O_BWO + i] = ldin(bw, (size_t)s * 256 + k, F); return;
  } i -= 4096;
  if (i < 16){ ws[O_BBO + i] = ldin(bb, i, F); return; } i -= 16;
  if (i < 4096){   // C_w transposed
    int k = i >> 4, s = i & 15;
    ws[O_CWO + i] = ldin(cw, (size_t)s * 256 + k, F); return;
  } i -= 4096;
  if (i < 16){ ws[O_CBO + i] = ldin(cb, i, F); return; } i -= 16;
  if (i < 65536){  // out_w transposed: dst[k*256+df] = src[df*256+k]
    int k = i >> 8, df = i & 255;
    ws[O_OW + i] = ldin(ow, (size_t)df * 256 + k, F); return;
  } i -= 65536;
  if (i < 256){ ws[O_OB + i] = ldin(ob, i, F); return; } i -= 256;
  if (i < 4096){ ws[O_AF + i] = -expf(ldin(alog, i, F)); return; } i -= 4096;
  if (i < 256){ ws[O_DD + i] = ldin(dvec, i, F); return; } i -= 256;
  if (i < 256){ ws[O_LNG + i] = ldin(lng, i, F); return; } i -= 256;
  if (i < 256){ ws[O_LNB + i] = ldin(lnb, i, F); }
}

// ---------------- K1: per-patch conv1 + MFMA conv2 (bf16 3-split) --------------------
// R7 = R6's no-spill retile (1 M-tile/wave, acc=32 regs) + R5's single-chunk-resident
// A (41.5 KB -> total LDS ~48 KB -> 2 blocks/CU at the 128-reg cap). Loop nest:
// pass-outer / chunk-inner; conv1 (432 FMA) reruns per (pass,chunk) with pin held
// in regs -- the doubled conv1 VALU overlaps the co-resident block's MFMA phase.
// MFMA order per acc element identical to R6 -> bitwise-identical feats.
__global__ __launch_bounds__(512, 4) void k_patch(const void* __restrict__ img,
                                                  const float* __restrict__ ws,
                                                  float* __restrict__ feats)
{
  __shared__ __align__(16) ushortb Abuf[2 * 10368]; // ONE chunk: hi [0], lo [10368] (41.5 KB)
  __shared__ float timg[768];      // 3KB input tile [3 c][256 px]
  __shared__ float pool8[8 * 128]; // per-wave (per-M-tile) pooled partials
  __shared__ float pm[128];        // pooled mean
  const int F = ((const int*)(ws + O_FLAG))[0];
  const float* W1 = ws + O_W1;  const float* B1 = ws + O_B1;
  const float* FCW = ws + O_FCW; const float* FCB = ws + O_FCB;
  const s16x8* BF = (const s16x8*)(ws + O_W2);   // fragment-major B

  int blk = blockIdx.x; int b = blk >> 10; int pidx = blk & 1023;
  int ph = pidx >> 5, pw = pidx & 31;
  int tid = threadIdx.x;

  // stage input tile (16x16x3) into LDS
  if (tid < 256){
    int y = tid >> 4, x = tid & 15;
    #pragma unroll
    for (int c = 0; c < 3; c++)
      timg[c * 256 + tid] =
        ldin(img, (((size_t)b * 3 + c) * 512 + (ph * 16 + y)) * 512 + (pw * 16 + x), F);
  }
  // zero A boundary rows (conv1 writes interior only, zeros persist across chunks)
  {
    uint4 z4 = make_uint4(0u, 0u, 0u, 0u);
    for (int r = tid; r < 324; r += 512){
      int y = r / 18, x = r - y * 18;
      if (y == 0 || y == 17 || x == 0 || x == 17){
        #pragma unroll
        for (int m = 0; m < 4; m++){
          *(uint4*)&Abuf[r * 32 + m * 8] = z4;
          *(uint4*)&Abuf[10368 + r * 32 + m * 8] = z4;
        }
      }
    }
  }
  __syncthreads();

  int wv = tid >> 6, ln = tid & 63;
  int l31 = ln & 31, lhi = ln >> 5;
  int xcol = ln & 15, yrow = l31 >> 4;
  int p = tid & 255, og = tid >> 8;
  int ii = p >> 4, jj = p & 15;

  // pin computed ONCE, held in 27 regs across all 4 conv1 invocations
  float pin[27];
  #pragma unroll
  for (int cc = 0; cc < 3; cc++)
    #pragma unroll
    for (int dy = 0; dy < 3; dy++)
      #pragma unroll
      for (int dx = 0; dx < 3; dx++){
        int y = ii + dy - 1, x = jj + dx - 1;
        bool ok = (y >= 0 && y < 16 && x >= 0 && x < 16);
        pin[cc * 9 + dy * 3 + dx] = ok ? timg[cc * 256 + y * 16 + x] : 0.f;
      }
  int rw = (ii + 1) * 18 + (jj + 1);
  int swz = ((rw >> 1) & 3) << 3;

  // 2 N-passes x 2 ic-chunks; conv1(chunk) before each MFMA phase
  #pragma unroll
  for (int pass = 0; pass < 2; pass++){
    fx16 acc0, acc1;
    #pragma unroll
    for (int r = 0; r < 16; r++){ acc0[r] = 0.f; acc1[r] = 0.f; }

    for (int c = 0; c < 2; c++){
      // conv1 chunk c: 32 oc; thread = (pixel p, half og of 16 oc)
      {
        int oc0 = c * 32 + og * 16;
        int w1base = __builtin_amdgcn_readfirstlane(oc0 * 27);
        const float* W1g = W1 + w1base;
        #pragma unroll
        for (int g = 0; g < 2; g++){
          float av[8];
          #pragma unroll
          for (int o = 0; o < 8; o++){
            float a = B1[oc0 + g * 8 + o];
            #pragma unroll
            for (int t = 0; t < 27; t++) a += W1g[(g * 8 + o) * 27 + t] * pin[t];
            av[o] = gelu_f(a);
          }
          unsigned int hp[4], lp[4];
          #pragma unroll
          for (int q = 0; q < 4; q++){
            float v0 = av[2 * q], v1 = av[2 * q + 1];
            ushortb h0 = f2bf(v0), h1 = f2bf(v1);
            float l0 = v0 - bf2f(h0), l1 = v1 - bf2f(h1);
            hp[q] = (unsigned int)h0 | ((unsigned int)h1 << 16);
            lp[q] = (unsigned int)f2bf(l0) | ((unsigned int)f2bf(l1) << 16);
          }
          int idx = rw * 32 + (((og * 2 + g) << 3) ^ swz);
          *(uint4*)&Abuf[idx] = make_uint4(hp[0], hp[1], hp[2], hp[3]);
          *(uint4*)&Abuf[10368 + idx] = make_uint4(lp[0], lp[1], lp[2], lp[3]);
        }
      }
      __syncthreads();

      // MFMA chunk c: 18 K-steps (9 taps x 2 k-subs of 16)
      {
        const s16x8* bfp = BF + (size_t)((c * 144 + pass * 4) * 64 + ln);
        for (int s = 0; s < 18; s++){
          int tap = s >> 1, ksub = s & 1;
          int dyq = tap / 3, dxq = tap - dyq * 3;
          int icq0 = (ksub << 1) + lhi;                 // 8-ic slot 0..3
          int rA = (wv * 2 + yrow + dyq) * 18 + (xcol + dxq);
          int iA = rA * 32 + ((icq0 ^ ((rA >> 1) & 3)) << 3);
          s16x8 fa_h = *(const s16x8*)&Abuf[iA];
          s16x8 fa_l = *(const s16x8*)&Abuf[10368 + iA];
          const s16x8* bq = bfp + (s << 9);
          s16x8 fb0h = bq[0];
          s16x8 fb0l = bq[64];
          s16x8 fb1h = bq[128];
          s16x8 fb1l = bq[192];
          acc0 = __builtin_amdgcn_mfma_f32_32x32x16_bf16(fa_h, fb0h, acc0, 0, 0, 0);
          acc1 = __builtin_amdgcn_mfma_f32_32x32x16_bf16(fa_h, fb1h, acc1, 0, 0, 0);
          acc0 = __builtin_amdgcn_mfma_f32_32x32x16_bf16(fa_l, fb0h, acc0, 0, 0, 0);
          acc1 = __builtin_amdgcn_mfma_f32_32x32x16_bf16(fa_l, fb1h, acc1, 0, 0, 0);
          acc0 = __builtin_amdgcn_mfma_f32_32x32x16_bf16(fa_h, fb0l, acc0, 0, 0, 0);
          acc1 = __builtin_amdgcn_mfma_f32_32x32x16_bf16(fa_h, fb1l, acc1, 0, 0, 0);
        }
      }
      __syncthreads();   // A dead before next chunk's conv1 overwrites it
    }

    // pool this pass's 2 N-tiles: C/D col oc = nt*32 + l31, rows = 16 regs x lhi.
    #pragma unroll
    for (int n = 0; n < 2; n++){
      int nt = pass * 2 + n;
      float bz = ws[O_B2 + nt * 32 + l31];
      float sum = 0.f;
      #pragma unroll
      for (int r = 0; r < 16; r++)
        sum += gelu_f(((n == 0) ? acc0[r] : acc1[r]) + bz);
      sum += __shfl_xor(sum, 32);
      if (lhi == 0) pool8[wv * 128 + nt * 32 + l31] = sum;
    }
  }
  __syncthreads();
  if (tid < 128){
    float sv = 0.f;
    #pragma unroll
    for (int w = 0; w < 8; w++) sv += pool8[w * 128 + tid];
    pm[tid] = sv * (1.f / 256.f);
  }
  __syncthreads();

  // fc 128 -> 256 (threads 0..255)
  if (tid < 256){
    int df = tid;
    float s = FCB[df];
    const float* wrow = FCW + (size_t)df * 128;
    #pragma unroll
    for (int k = 0; k < 128; k += 4)
      s += wrow[k] * pm[k] + wrow[k + 1] * pm[k + 1]
         + wrow[k + 2] * pm[k + 2] + wrow[k + 3] * pm[k + 3];
    feats[((size_t)(b * 1024 + pidx)) * 256 + df] = s;
  }
}

// ---------------- K3: structure (rsem fused + Boruvka MST + adjacency + level BFS) ---
__device__ __forceinline__ void edge_uv(int e, int& u, int& v){
  if (e < 1953){
    int i = e / 63; int k = e - i * 63;
    if (k < 62){ int j = k >> 1; u = i * 32 + j; v = (k & 1) ? u + 32 : u + 1; }
    else { u = i * 32 + 31; v = u + 32; }
  } else { u = 31 * 32 + (e - 1953); v = u + 1; }
}

__global__ __launch_bounds__(1024) void k_struct(float* __restrict__ ws)
{
  __shared__ float s_ninv[1024];
  __shared__ float s_w[NEDGE];
  __shared__ float s_r[1024];
  __shared__ int   s_comp[1024];
  __shared__ int   s_link[1024];
  __shared__ int   s_link2[1024];
  __shared__ unsigned long long s_best[1024];
  __shared__ unsigned char  s_mst[NEDGE];
  __shared__ unsigned short s_adj[1024 * 4];
  __shared__ unsigned char  s_deg[1024];
  __shared__ unsigned short s_bfs[1024];
  __shared__ short          s_parof[1024];
  __shared__ unsigned short s_o2b[1024];
  __shared__ unsigned short s_cur[1024];
  __shared__ unsigned short s_nxt[1024];
  __shared__ unsigned short s_off[1025];
  __shared__ unsigned short s_loff2[1026];
  __shared__ unsigned long long s_rootkey;
  __shared__ int s_ncomp, s_cursz, s_bfscnt, s_nextsz, s_nlvl;

  int b = blockIdx.x; int tid = threadIdx.x;
  const float* feats = ws + O_FEATS + (size_t)b * NP * DFEAT;

  // norms + fused r_sem + defensive init
  {
    const float4* f4 = (const float4*)(feats + (size_t)tid * 256);
    const float4* g4 = (const float4*)(ws + O_GPROJ + b * 256);
    float d = 0.f, gdot = 0.f;
    for (int k = 0; k < 64; k++){
      float4 q = f4[k]; float4 g = g4[k];
      d += q.x*q.x + q.y*q.y + q.z*q.z + q.w*q.w;
      gdot += q.x*g.x + q.y*g.y + q.z*g.z + q.w*g.w;
    }
    s_ninv[tid] = 1.f / fmaxf(sqrtf(d), 1e-12f);
    float r = 1.f / (1.f + expf(-gdot * (1.f / 16.f)));
    s_r[tid] = r;
    ws[O_RSEM + b * NP + tid] = r;      // k_xdelta consumes this
    s_comp[tid] = tid;
    s_deg[tid] = 0;
    s_bfs[tid] = (unsigned short)tid;
    s_o2b[tid] = (unsigned short)tid;
    s_parof[tid] = -1;
  }
  for (int e = tid; e < NEDGE; e += 1024) s_mst[e] = 0;
  __syncthreads();

  // edge weights
  for (int e = tid; e < NEDGE; e += 1024){
    int u, v; edge_uv(e, u, v);
    const float4* fu = (const float4*)(feats + (size_t)u * 256);
    const float4* fv = (const float4*)(feats + (size_t)v * 256);
    float d = 0.f;
    for (int k = 0; k < 64; k++){ float4 a = fu[k], c = fv[k]; d += a.x*c.x + a.y*c.y + a.z*c.z + a.w*c.w; }
    float cosv = d * s_ninv[u] * s_ninv[v];
    s_w[e] = (1.f - s_r[u]) * (1.f - s_r[v]) * (-cosv) + 1e-6f;
  }
  __syncthreads();

  // Boruvka rounds (root chase instead of fixed pointer-jumping: exact, fewer barriers)
  for (int round = 0; round < 12; round++){
    s_best[tid] = ~0ull;
    __syncthreads();
    for (int e = tid; e < NEDGE; e += 1024){
      int u, v; edge_uv(e, u, v);
      int cu = s_comp[u], cv = s_comp[v];
      if (cu != cv){
        unsigned long long key = (((unsigned long long)f2sort(s_w[e])) << 32) | (unsigned int)e;
        atomicMin(&s_best[cu], key);
        atomicMin(&s_best[cv], key);
      }
    }
    __syncthreads();
    int l = tid;
    if (s_comp[tid] == tid && s_best[tid] != ~0ull){
      int e = (int)(s_best[tid] & 0xffffffffu);
      int u, v; edge_uv(e, u, v);
      s_mst[e] = 1;
      int cu = s_comp[u], cv = s_comp[v];
      l = (cu == tid) ? cv : cu;
    }
    s_link[tid] = l;
    __syncthreads();
    if (l != tid && s_link[l] == tid && tid < l) s_link[tid] = tid; // break 2-cycles
    __syncthreads();
    // chase to root (links static: only 2-cycles existed, now broken -> acyclic)
    {
      int x = tid;
      int p = s_link[x];
      while (p != x){ x = p; p = s_link[x]; }
      s_link2[tid] = x;
    }
    __syncthreads();
    s_comp[tid] = s_link2[s_comp[tid]];
    if (tid == 0) s_ncomp = 0;
    __syncthreads();
    if (s_comp[tid] == tid) atomicAdd(&s_ncomp, 1);
    __syncthreads();
    if (s_ncomp == 1) break;
    __syncthreads();
  }
  __syncthreads();

  // weight-ordered adjacency (== Kruskal insertion order for unique MST)
  {
    int v = tid; int i = v >> 5, j = v & 31;
    float wloc[4]; int nloc[4]; int d = 0;
    if (j > 0){ int e = (i < 31) ? (i * 63 + 2 * (j - 1)) : (1953 + (j - 1));
      if (s_mst[e]){ wloc[d] = s_w[e]; nloc[d] = v - 1; d++; } }
    if (j < 31){ int e = (i < 31) ? (i * 63 + 2 * j) : (1953 + j);
      if (s_mst[e]){ wloc[d] = s_w[e]; nloc[d] = v + 1; d++; } }
    if (i > 0){ int e = (i - 1) * 63 + ((j < 31) ? (2 * j + 1) : 62);
      if (s_mst[e]){ wloc[d] = s_w[e]; nloc[d] = v - 32; d++; } }
    if (i < 31){ int e = i * 63 + ((j < 31) ? (2 * j + 1) : 62);
      if (s_mst[e]){ wloc[d] = s_w[e]; nloc[d] = v + 32; d++; } }
    for (int a = 1; a < d; a++){
      float wv = wloc[a]; int nv = nloc[a]; int c = a - 1;
      while (c >= 0 && wloc[c] > wv){ wloc[c+1] = wloc[c]; nloc[c+1] = nloc[c]; c--; }
      wloc[c+1] = wv; nloc[c+1] = nv;
    }
    s_deg[v] = (unsigned char)d;
    for (int a = 0; a < d; a++) s_adj[v * 4 + a] = (unsigned short)nloc[a];
  }
  // root = argmax r (first index on ties)
  if (tid == 0) s_rootkey = 0ull;
  __syncthreads();
  {
    unsigned long long key = (((unsigned long long)f2sort(s_r[tid])) << 32) | (unsigned int)(1023 - tid);
    atomicMax(&s_rootkey, key);
  }
  __syncthreads();
  int root = 1023 - (int)(s_rootkey & 0xffffffffu);

  // level-parallel tree BFS (records level offsets for k_scan)
  if (tid == 0){
    s_bfs[0] = (unsigned short)root; s_o2b[root] = 0; s_parof[root] = -1;
    s_cur[0] = (unsigned short)root; s_cursz = 1; s_bfscnt = 1; s_nlvl = 0;
  }
  __syncthreads();
  for (int lev = 0; lev < 1024; lev++){
    int csz = s_cursz;
    if (csz <= 0) break;
    // wave-parallel exclusive scan of child counts
    if (tid < 64){
      int runbase = 0;
      for (int t0 = 0; t0 < csz; t0 += 64){
        int t = t0 + tid;
        int cnt = 0;
        if (t < csz){
          int n = s_cur[t];
          cnt = (int)s_deg[n] - (s_parof[n] >= 0 ? 1 : 0);
        }
        int v = cnt;
        #pragma unroll
        for (int off = 1; off < 64; off <<= 1){
          int u2 = __shfl_up(v, off);
          if (tid >= off) v += u2;
        }
        if (t < csz) s_off[t] = (unsigned short)(runbase + v - cnt);
        runbase += __shfl(v, 63);
      }
      if (tid == 0){
        if (s_nlvl < 1025){ s_loff2[s_nlvl] = (unsigned short)(s_bfscnt - csz); }
        s_nlvl++;
        s_nextsz = runbase;
      }
    }
    __syncthreads();
    if (tid < csz){
      int n = s_cur[tid]; int base = s_off[tid]; int k = 0;
      int pn = s_parof[n]; int dg = s_deg[n];
      for (int a = 0; a < dg; a++){
        int c = s_adj[n * 4 + a];
        if (c == pn) continue;
        s_parof[c] = (short)n;
        if (base + k < 1024) s_nxt[base + k] = (unsigned short)c;
        int pos = s_bfscnt + base + k;
        if (pos < 1024){
          s_bfs[pos] = (unsigned short)c;
          s_o2b[c] = (unsigned short)pos;
        }
        k++;
      }
    }
    __syncthreads();
    if (tid == 0){ s_bfscnt += s_nextsz; s_cursz = (s_nextsz > 1024) ? 1024 : s_nextsz; }
    __syncthreads();
    if (tid < s_cursz) s_cur[tid] = s_nxt[tid];
    __syncthreads();
  }
  __syncthreads();

  int* BFSo = (int*)(ws + O_BFS);
  int* PARo = (int*)(ws + O_PAR);
  {
    int node = s_bfs[tid] & 1023;
    BFSo[b * 1024 + tid] = node;
    int p = s_parof[node];
    PARo[b * 1024 + tid] = (p < 0) ? -1 : (int)(s_o2b[p] & 1023);
  }
  // export level table: [nlvl, loff[0..nlvl]] (loff[nlvl] = NP)
  {
    int* LVLo = (int*)(ws + O_LVL) + b * 1040;
    int nl = s_nlvl; if (nl > 1024) nl = 1024;
    if (tid == 0){ LVLo[0] = nl; LVLo[1 + nl] = NP; }
    if (tid < nl) LVLo[1 + tid] = (int)s_loff2[tid];
  }
}

// ---------------- K4: X, delta, Bp, Cp (k-major coalesced weight reads) --------------
__global__ __launch_bounds__(256) void k_xdelta(float* __restrict__ ws)
{
  __shared__ float xs[256];
  int blk = blockIdx.x; int b = blk >> 10, i = blk & 1023; int df = threadIdx.x;
  const int* BFSo = (const int*)(ws + O_BFS);
  int node = BFSo[b * 1024 + i] & 1023;
  float rs = ws[O_RSEM + b * 1024 + node];
  float xv = ws[O_FEATS + ((size_t)(b * 1024 + node)) * 256 + df] + rs * ws[O_GPRIM + b * 256 + df];
  xs[df] = xv;
  ws[O_X + ((size_t)(b * 1024 + i)) * 256 + df] = xv;
  __syncthreads();
  {
    const float* WT = ws + O_WDW;
    float z = ws[O_WDB + df];
    #pragma unroll 8
    for (int k = 0; k < 256; k++)
      z += WT[(size_t)k * 256 + df] * xs[k];
    float sp = fmaxf(z, 0.f) + log1pf(expf(-fabsf(z)));
    ws[O_DELTA + ((size_t)(b * 1024 + i)) * 256 + df] = sp * (1.f + 2.f * rs);
  }
  if (df < 32){
    int s = df & 15;
    const float* WT = ws + ((df < 16) ? O_BWO : O_CWO);   // [k][s]
    float a = ws[((df < 16) ? O_BBO : O_CBO) + s];
    #pragma unroll 8
    for (int k = 0; k < 256; k++) a += WT[k * 16 + s] * xs[k];
    ws[((df < 16) ? O_BP : O_CP) + (size_t)(b * 1024 + i) * 16 + s] = a;
  }
}

// ---------------- K5: tree scan, LEVEL-PARALLEL, 256 threads -------------------------
__global__ __launch_bounds__(256) void k_scan(float* __restrict__ ws)
{
  __shared__ float h[NP * DSTATE];   // 64 KB: h[pos][s]
  __shared__ float xs[NP];
  __shared__ float ds[NP];
  __shared__ int   par_s[NP];
  __shared__ int   bfs_s[NP];
  int blk = blockIdx.x; int b = blk >> 8, f = blk & 255;
  int tid = threadIdx.x;
  int g = tid >> 4, s = tid & 15;
  const int* PARo = (const int*)(ws + O_PAR);
  const int* BFSo = (const int*)(ws + O_BFS);
  const int* LVLo = (const int*)(ws + O_LVL) + b * 1040;
  for (int i = tid; i < NP; i += 256){
    xs[i] = ws[O_X     + ((size_t)(b * NP + i)) * DFEAT + f];
    ds[i] = ws[O_DELTA + ((size_t)(b * NP + i)) * DFEAT + f];
    par_s[i] = PARo[b * NP + i];
    bfs_s[i] = BFSo[b * NP + i] & 1023;
  }
  __syncthreads();

  int nlvl = LVLo[0];
  bool degen = (nlvl < 1 || nlvl > NP);
  if (degen) nlvl = NP;               // fallback: one node per level == serial order

  float Aln = ws[O_AF + f * 16 + s];
  float Dv  = ws[O_DD + f];
  const float* Bp = ws + O_BP + (size_t)b * NP * DSTATE;
  const float* Cp = ws + O_CP + (size_t)b * NP * DSTATE;
  float* Yr = ws + O_YR + (size_t)b * NP * DFEAT;

  for (int l = 0; l < nlvl; l++){
    int o0, o1;
    if (degen){ o0 = l; o1 = l + 1; }
    else {
      o0 = LVLo[1 + l]; o1 = LVLo[2 + l];
      o0 = (o0 < 0) ? 0 : ((o0 > NP) ? NP : o0);
      o1 = (o1 < o0) ? o0 : ((o1 > NP) ? NP : o1);
    }
    for (int i = o0 + g; i < o1; i += 16){
      int p = par_s[i];
      float d = ds[i], x = xs[i];
      float hp = (p >= 0 && p < i) ? h[p * 16 + s] : 0.f;
      float hn = expf(d * Aln) * hp + d * Bp[i * 16 + s] * x;
      h[i * 16 + s] = hn;
      float t = hn * Cp[i * 16 + s];
      t += __shfl_xor(t, 1); t += __shfl_xor(t, 2);
      t += __shfl_xor(t, 4); t += __shfl_xor(t, 8);
      if (s == 0) Yr[(size_t)bfs_s[i] * DFEAT + f] = t + Dv * x;
    }
    __syncthreads();   // orders level l writes vs l+1 reads
  }
}

// ---------------- K6: out GEMM (k-major coalesced) + LayerNorm -> out dtype ----------
__global__ __launch_bounds__(256) void k_outln(const float* __restrict__ ws,
                                               void* __restrict__ out)
{
  __shared__ float yl[256];
  __shared__ float red[8];
  const int F = ((const int*)(ws + O_FLAG))[0];
  int blk = blockIdx.x; int b = blk >> 10, p = blk & 1023; int df = threadIdx.x;
  yl[df] = ws[O_YR + ((size_t)(b * 1024 + p)) * 256 + df];
  __syncthreads();
  const float* OT = ws + O_OW;   // [k][df]
  float a = ws[O_OB + df];
  #pragma unroll 8
  for (int k = 0; k < 256; k++)
    a += OT[(size_t)k * 256 + df] * yl[k];
  int lane = df & 63, wid = df >> 6;
  float t = a;
  t += __shfl_xor(t, 1); t += __shfl_xor(t, 2);  t += __shfl_xor(t, 4);
  t += __shfl_xor(t, 8); t += __shfl_xor(t, 16); t += __shfl_xor(t, 32);
  if (lane == 0) red[wid] = t;
  __syncthreads();
  float mu = (red[0] + red[1] + red[2] + red[3]) * (1.f / 256.f);
  float dv = a - mu;
  float t2 = dv * dv;
  t2 += __shfl_xor(t2, 1); t2 += __shfl_xor(t2, 2);  t2 += __shfl_xor(t2, 4);
  t2 += __shfl_xor(t2, 8); t2 += __shfl_xor(t2, 16); t2 += __shfl_xor(t2, 32);
  if (lane == 0) red[4 + wid] = t2;
  __syncthreads();
  float var = (red[4] + red[5] + red[6] + red[7]) * (1.f / 256.f);
  float o = ws[O_LNG + df] * dv / sqrtf(var + 1e-5f) + ws[O_LNB + df];
  size_t idx = ((size_t)(b * 1024 + p)) * 256 + df;
  if (F) ((ushortb*)out)[idx] = f2bf(o);
  else   ((float*)out)[idx]   = o;
}

// ---------------- launch ----------------
extern "C" void kernel_launch(void* const* d_in, const int* in_sizes, int n_in,
                              void* d_out, int out_size, void* d_ws, size_t ws_size,
                              hipStream_t stream)
{
  (void)in_sizes; (void)n_in; (void)out_size; (void)ws_size;
  const void* img   = d_in[0];
  const void* lang  = d_in[1];
  const void* c1w   = d_in[2];
  const void* c1b   = d_in[3];
  const void* c2w   = d_in[4];
  const void* c2b   = d_in[5];
  const void* fcw   = d_in[6];
  const void* fcb   = d_in[7];
  const void* wgate = d_in[8];
  const void* wgp   = d_in[9];
  const void* alog  = d_in[10];
  const void* dvec  = d_in[11];
  const void* bw    = d_in[12];
  const void* bb    = d_in[13];
  const void* cw    = d_in[14];
  const void* cb    = d_in[15];
  const void* wdw   = d_in[16];
  const void* wdb   = d_in[17];
  const void* ow    = d_in[18];
  const void* ob    = d_in[19];
  const void* lng   = d_in[20];
  const void* lnb   = d_in[21];
  float* ws = (float*)d_ws;

  k_sniff<<<1, 256, 0, stream>>>(img, ws);
  k_convert<<<990 + 2048 + 256, 256, 0, stream>>>(c1w, c1b, c2w, c2b, fcw, fcb, alog, dvec,
                                                  bw, bb, cw, cb, wdw, wdb, ow, ob, lng, lnb,
                                                  lang, wgate, wgp, ws);
  k_patch<<<2048, 512, 0, stream>>>(img, ws, ws + O_FEATS);
  k_struct<<<2, 1024, 0, stream>>>(ws);
  k_xdelta<<<2048, 256, 0, stream>>>(ws);
  k_scan<<<NB * DFEAT, 256, 0, stream>>>(ws);
  k_outln<<<2048, 256, 0, stream>>>(ws, d_out);
}